// Round 10
// baseline (1268.567 us; speedup 1.0000x reference)
//
#include <hip/hip_runtime.h>
#include <hip/hip_bf16.h>
#include <math.h>

#define T_SEQ   3072
#define C_DIM   1024
#define NH      16
#define NKV     4
#define HD      64
#define HI      16
#define DI      32
#define LOCAL_W 128
#define TOPK    1536
#define SELQ0   (TOPK - LOCAL_W + 1)   /* 1409 */
#define RMS_EPS 1.1920929e-07f
#define LOGEPS  -13.815510558f
#define SCALE   0.125f
#define MASKW   (T_SEQ / 32)
#define QKVI_N  2048                   /* fused projection width: q|k|v|iq */

typedef __bf16 bf16_t;
typedef __bf16 bf16x8 __attribute__((ext_vector_type(8)));
typedef float  f32x4  __attribute__((ext_vector_type(4)));

// ---------------------------------------------------------------------------
// W[K=1024][N] fp32  ->  Wt[N][K=1024] bf16 (transpose + convert), 64x64 tiles
// ---------------------------------------------------------------------------
__global__ __launch_bounds__(256) void transp_conv(const float* __restrict__ W,
                                                   bf16_t* __restrict__ Wt, int N) {
    __shared__ float t[64][65];
    int n0 = blockIdx.x * 64, k0 = blockIdx.y * 64;
#pragma unroll
    for (int it = 0; it < 16; ++it) {
        int flat = it * 256 + threadIdx.x;
        int i = flat >> 6, j = flat & 63;
        t[i][j] = W[(size_t)(k0 + i) * N + n0 + j];
    }
    __syncthreads();
#pragma unroll
    for (int it = 0; it < 16; ++it) {
        int flat = it * 256 + threadIdx.x;
        int n = flat >> 6, kk = flat & 63;
        Wt[(size_t)(n0 + n) * 1024 + k0 + kk] = (bf16_t)t[kk][n];
    }
}

// ---------------------------------------------------------------------------
// V region of qkvi (fp32 [t][1280 + kvh*64 + d]) -> Vtg bf16 [kvh*64+d][T]
// ---------------------------------------------------------------------------
__global__ __launch_bounds__(256) void transp_v(const float* __restrict__ qkvi,
                                                bf16_t* __restrict__ Vtg) {
    __shared__ float t[64][65];
    int t0 = blockIdx.x * 64, kvh = blockIdx.y;
#pragma unroll
    for (int it = 0; it < 16; ++it) {
        int flat = it * 256 + threadIdx.x;
        int i = flat >> 6, j = flat & 63;       // i: t-row, j: dim
        t[i][j] = qkvi[(size_t)(t0 + i) * QKVI_N + 1280 + kvh * HD + j];
    }
    __syncthreads();
#pragma unroll
    for (int it = 0; it < 16; ++it) {
        int flat = it * 256 + threadIdx.x;
        int dd = flat >> 6, tt = flat & 63;
        Vtg[(size_t)(kvh * HD + dd) * T_SEQ + t0 + tt] = (bf16_t)t[tt][dd];
    }
}

// ---------------------------------------------------------------------------
// bf16 MFMA GEMM: C[M][N] = A[M][1024] @ Bt[N][1024]^T, fp32 out.
// A_F32: A is fp32 and converted to bf16 during LDS staging.
// 128x128 tile, BK=64, 4 waves (2x2), wave tile 64x64, 16x16x32 MFMA.
// LDS XOR-swizzle (slot ^= row&7). M, N multiples of 128.
// ---------------------------------------------------------------------------
template<bool A_F32>
__global__ __launch_bounds__(256) void gemm_mfma_t(const void* __restrict__ Ap,
                                                   const bf16_t* __restrict__ Bt,
                                                   float* __restrict__ C, int N) {
    __shared__ __align__(16) bf16_t As[128 * 64];
    __shared__ __align__(16) bf16_t Bs[128 * 64];
    const int tid = threadIdx.x;
    const int m0 = blockIdx.y * 128, n0 = blockIdx.x * 128;
    const int wid = tid >> 6, lane = tid & 63;
    const int wr = wid >> 1, wc = wid & 1;
    const int fr = lane & 15, fq = lane >> 4;

    f32x4 acc[4][4];
#pragma unroll
    for (int i = 0; i < 4; ++i)
#pragma unroll
        for (int j = 0; j < 4; ++j) acc[i][j] = (f32x4){0.f, 0.f, 0.f, 0.f};

    for (int k0 = 0; k0 < 1024; k0 += 64) {
        __syncthreads();
#pragma unroll
        for (int s = tid; s < 1024; s += 256) {
            int row = s >> 3, slot = s & 7;
            int sw = slot ^ (row & 7);
            bf16x8 av;
            if constexpr (A_F32) {
                const float* A = (const float*)Ap;
                const float* src = &A[(size_t)(m0 + row) * 1024 + k0 + slot * 8];
                float4 a = *reinterpret_cast<const float4*>(src);
                float4 b = *reinterpret_cast<const float4*>(src + 4);
                av[0] = (bf16_t)a.x; av[1] = (bf16_t)a.y; av[2] = (bf16_t)a.z; av[3] = (bf16_t)a.w;
                av[4] = (bf16_t)b.x; av[5] = (bf16_t)b.y; av[6] = (bf16_t)b.z; av[7] = (bf16_t)b.w;
            } else {
                const bf16_t* A = (const bf16_t*)Ap;
                av = *reinterpret_cast<const bf16x8*>(&A[(size_t)(m0 + row) * 1024 + k0 + slot * 8]);
            }
            *reinterpret_cast<bf16x8*>(&As[row * 64 + sw * 8]) = av;
            bf16x8 bv = *reinterpret_cast<const bf16x8*>(&Bt[(size_t)(n0 + row) * 1024 + k0 + slot * 8]);
            *reinterpret_cast<bf16x8*>(&Bs[row * 64 + sw * 8]) = bv;
        }
        __syncthreads();
#pragma unroll
        for (int kk = 0; kk < 2; ++kk) {
            bf16x8 af[4], bfr[4];
#pragma unroll
            for (int i = 0; i < 4; ++i) {
                int arow = wr * 64 + i * 16 + fr;
                int aslot = (kk * 4 + fq) ^ (arow & 7);
                af[i] = *reinterpret_cast<const bf16x8*>(&As[arow * 64 + aslot * 8]);
                int brow = wc * 64 + i * 16 + fr;
                int bslot = (kk * 4 + fq) ^ (brow & 7);
                bfr[i] = *reinterpret_cast<const bf16x8*>(&Bs[brow * 64 + bslot * 8]);
            }
#pragma unroll
            for (int i = 0; i < 4; ++i)
#pragma unroll
                for (int j = 0; j < 4; ++j)
                    acc[i][j] = __builtin_amdgcn_mfma_f32_16x16x32_bf16(af[i], bfr[j], acc[i][j], 0, 0, 0);
        }
    }
#pragma unroll
    for (int i = 0; i < 4; ++i)
#pragma unroll
        for (int j = 0; j < 4; ++j)
#pragma unroll
            for (int r = 0; r < 4; ++r) {
                int row = m0 + wr * 64 + i * 16 + fq * 4 + r;
                int col = n0 + wc * 64 + j * 16 + fr;
                C[(size_t)row * N + col] = acc[i][j][r];
            }
}

// ---------------------------------------------------------------------------
// Generic fp32 GEMM (skinny ik/iw projections, N=32/16 — selection path
// stays fp32 to avoid top-k flips from projection rounding)
// ---------------------------------------------------------------------------
__global__ __launch_bounds__(256) void gemm_f32(const float* __restrict__ A,
                                                const float* __restrict__ W,
                                                float* __restrict__ Cmat, int N) {
    __shared__ float As[8][128];
    __shared__ float Ws[8][128];
    const int K = C_DIM;
    const int tid = threadIdx.x;
    const int tx = tid & 15, ty = tid >> 4;
    const int m0 = blockIdx.y * 128;
    const int n0 = blockIdx.x * 128;

    float acc[8][8];
#pragma unroll
    for (int i = 0; i < 8; ++i)
#pragma unroll
        for (int j = 0; j < 8; ++j) acc[i][j] = 0.f;

    for (int k0 = 0; k0 < K; k0 += 8) {
        __syncthreads();
        {
            int row = tid >> 1, kq = tid & 1;
            float4 a = *reinterpret_cast<const float4*>(&A[(size_t)(m0 + row) * K + k0 + kq * 4]);
            As[kq * 4 + 0][row] = a.x; As[kq * 4 + 1][row] = a.y;
            As[kq * 4 + 2][row] = a.z; As[kq * 4 + 3][row] = a.w;
        }
        {
            int kk = tid >> 5, nq = tid & 31;
            int n = n0 + nq * 4;
            float4 w;
            if (n + 3 < N) {
                w = *reinterpret_cast<const float4*>(&W[(size_t)(k0 + kk) * N + n]);
            } else {
                w.x = (n + 0 < N) ? W[(size_t)(k0 + kk) * N + n + 0] : 0.f;
                w.y = (n + 1 < N) ? W[(size_t)(k0 + kk) * N + n + 1] : 0.f;
                w.z = (n + 2 < N) ? W[(size_t)(k0 + kk) * N + n + 2] : 0.f;
                w.w = (n + 3 < N) ? W[(size_t)(k0 + kk) * N + n + 3] : 0.f;
            }
            Ws[kk][nq * 4 + 0] = w.x; Ws[kk][nq * 4 + 1] = w.y;
            Ws[kk][nq * 4 + 2] = w.z; Ws[kk][nq * 4 + 3] = w.w;
        }
        __syncthreads();
#pragma unroll
        for (int kk = 0; kk < 8; ++kk) {
            float4 a0 = *reinterpret_cast<const float4*>(&As[kk][ty * 8]);
            float4 a1 = *reinterpret_cast<const float4*>(&As[kk][ty * 8 + 4]);
            float4 b0 = *reinterpret_cast<const float4*>(&Ws[kk][tx * 8]);
            float4 b1 = *reinterpret_cast<const float4*>(&Ws[kk][tx * 8 + 4]);
            float av[8] = {a0.x, a0.y, a0.z, a0.w, a1.x, a1.y, a1.z, a1.w};
            float bv[8] = {b0.x, b0.y, b0.z, b0.w, b1.x, b1.y, b1.z, b1.w};
#pragma unroll
            for (int i = 0; i < 8; ++i)
#pragma unroll
                for (int j = 0; j < 8; ++j)
                    acc[i][j] = fmaf(av[i], bv[j], acc[i][j]);
        }
    }
#pragma unroll
    for (int i = 0; i < 8; ++i) {
        int r = m0 + ty * 8 + i;
#pragma unroll
        for (int j = 0; j < 8; ++j) {
            int c = n0 + tx * 8 + j;
            if (c < N) Cmat[(size_t)r * N + c] = acc[i][j];
        }
    }
}

// ---------------------------------------------------------------------------
// RoPE + RMS norm, in place, strided fused-buffer layout.
// ---------------------------------------------------------------------------
__global__ __launch_bounds__(256) void rope_rms(float* __restrict__ data,
                                                const float* __restrict__ cosb,
                                                const float* __restrict__ sinb,
                                                int nheads, int rowstride, int coloff) {
    int idx = blockIdx.x * blockDim.x + threadIdx.x;
    if (idx >= T_SEQ * nheads) return;
    int t = idx / nheads, hh = idx % nheads;
    float* p = data + (size_t)t * rowstride + coloff + hh * HD;
    float o[HD];
    float ss = 0.f;
#pragma unroll
    for (int d = 0; d < 32; ++d) {
        float x1 = p[d], x2 = p[d + 32];
        float c = cosb[t * 32 + d], s = sinb[t * 32 + d];
        float a = x1 * c + x2 * s;
        float b = x2 * c - x1 * s;
        o[d] = a; o[d + 32] = b;
        ss += a * a + b * b;
    }
    float r = 1.0f / sqrtf(ss * (1.0f / HD) + RMS_EPS);
#pragma unroll
    for (int d = 0; d < HD; ++d) p[d] = o[d] * r;
}

// ---------------------------------------------------------------------------
// Importance + exact top-R radix select (rows q in [SELQ0, T)).
// ---------------------------------------------------------------------------
__global__ __launch_bounds__(256) void imp_select(const float* __restrict__ qkvi,
                                                  const float* __restrict__ ik,
                                                  const float* __restrict__ iw,
                                                  unsigned* __restrict__ selmask) {
    const int q = SELQ0 + blockIdx.x;
    const int tid = threadIdx.x;
    __shared__ float iqs[HI * DI];
    __shared__ float iws[HI];
    __shared__ unsigned keys[T_SEQ];
    __shared__ unsigned hist[256];
    __shared__ unsigned gtw[MASKW], eqw[MASKW];
    __shared__ int s_digit, s_need;

    for (int i = tid; i < HI * DI; i += 256) iqs[i] = qkvi[(size_t)q * QKVI_N + 1536 + i];
    if (tid < HI) iws[tid] = iw[(size_t)q * HI + tid];
    __syncthreads();

    for (int k = tid; k < q; k += 256) {
        float ikr[DI];
#pragma unroll
        for (int p4 = 0; p4 < DI / 4; ++p4) {
            float4 v = *reinterpret_cast<const float4*>(&ik[(size_t)k * DI + p4 * 4]);
            ikr[p4 * 4 + 0] = v.x; ikr[p4 * 4 + 1] = v.y;
            ikr[p4 * 4 + 2] = v.z; ikr[p4 * 4 + 3] = v.w;
        }
        float impv = 0.f;
#pragma unroll
        for (int h = 0; h < HI; ++h) {
            float d = 0.f;
#pragma unroll
            for (int dd = 0; dd < DI; ++dd) d = fmaf(iqs[h * DI + dd], ikr[dd], d);
            impv = fmaf(iws[h], fmaxf(d, 0.f), impv);
        }
        unsigned u = __float_as_uint(impv);
        keys[k] = (u & 0x80000000u) ? ~u : (u | 0x80000000u);
    }
    __syncthreads();

    const int F = min(LOCAL_W, T_SEQ - q);
    int need = TOPK - F;
    unsigned pref = 0;
    for (int b = 3; b >= 0; --b) {
        hist[tid] = 0;
        __syncthreads();
        unsigned above = (b == 3) ? 0u : (~0u << ((b + 1) * 8));
        for (int k = tid; k < q; k += 256) {
            unsigned key = keys[k];
            if ((key & above) == (pref & above))
                atomicAdd(&hist[(key >> (b * 8)) & 255u], 1u);
        }
        __syncthreads();
        if (tid == 0) {
            int cum = 0, digit = 0;
            for (int bin = 255; bin >= 0; --bin) {
                cum += (int)hist[bin];
                if (cum >= need) { digit = bin; s_need = need - (cum - (int)hist[bin]); break; }
            }
            s_digit = digit;
        }
        __syncthreads();
        pref |= ((unsigned)s_digit) << (b * 8);
        need = s_need;
        __syncthreads();
    }
    const unsigned V = pref;
    const int slots = need;

    for (int w = tid; w < MASKW; w += 256) {
        unsigned g = 0, e = 0;
        int kbase = w * 32;
#pragma unroll 4
        for (int bit = 0; bit < 32; ++bit) {
            int k = kbase + bit;
            if (k < q) {
                unsigned key = keys[k];
                if (key > V) g |= (1u << bit);
                else if (key == V) e |= (1u << bit);
            }
        }
        gtw[w] = g; eqw[w] = e;
    }
    __syncthreads();
    if (tid == 0) {
        int rem = slots;
        for (int w = 0; w < MASKW && rem > 0; ++w) {
            unsigned e = eqw[w];
            if (!e) continue;
            int pc = __popc(e);
            if (pc <= rem) { gtw[w] |= e; rem -= pc; }
            else {
                unsigned sel = 0;
                for (int i = 0; i < rem; ++i) { unsigned lb = e & (~e + 1u); sel |= lb; e ^= lb; }
                gtw[w] |= sel; rem = 0;
            }
        }
    }
    __syncthreads();
    for (int w = tid; w < MASKW; w += 256) selmask[(size_t)q * MASKW + w] = gtw[w];
}

// ---------------------------------------------------------------------------
// MFMA attention: one block per (64-q-tile, head), 4 waves, KT=64 key tiles.
// QK^T and PV via 16x16x32 bf16 MFMA; bias + online softmax fp32 via Sb LDS.
// Wave w owns q-rows [w*16, w*16+16) and all 64 cols of its S / O tiles.
// Sb padded to [64][68]: row stride 272B is 16B-aligned -> float4 P reads.
// ---------------------------------------------------------------------------
__global__ __launch_bounds__(256) void attn_mfma(const float* __restrict__ qkvi,
                                                 const bf16_t* __restrict__ Vtg,
                                                 const unsigned* __restrict__ selmask,
                                                 float* __restrict__ yb) {
    const int q0 = blockIdx.x * 64;
    const int h = blockIdx.y;
    const int kvh = h >> 2;
    const int tid = threadIdx.x;
    const int wid = tid >> 6, lane = tid & 63;
    const int fr = lane & 15, fq = lane >> 4;

    __shared__ __align__(16) bf16_t Qs[64 * 64];
    __shared__ __align__(16) bf16_t Ks[64 * 64];
    __shared__ __align__(16) bf16_t Vts[64 * 64];   // [d][key]
    __shared__ __align__(16) float Sb[64][68];
    __shared__ float mrow[64], lrow[64], arow[64];

    // stage Q (scaled) once: 64 rows x 8 slots of bf16x8, XOR-swizzled
#pragma unroll
    for (int it = 0; it < 2; ++it) {
        int s = it * 256 + tid;
        int row = s >> 3, slot = s & 7;
        const float* src = &qkvi[(size_t)(q0 + row) * QKVI_N + h * HD + slot * 8];
        float4 a = *reinterpret_cast<const float4*>(src);
        float4 b = *reinterpret_cast<const float4*>(src + 4);
        bf16x8 v;
        v[0] = (bf16_t)(a.x * SCALE); v[1] = (bf16_t)(a.y * SCALE);
        v[2] = (bf16_t)(a.z * SCALE); v[3] = (bf16_t)(a.w * SCALE);
        v[4] = (bf16_t)(b.x * SCALE); v[5] = (bf16_t)(b.y * SCALE);
        v[6] = (bf16_t)(b.z * SCALE); v[7] = (bf16_t)(b.w * SCALE);
        *reinterpret_cast<bf16x8*>(&Qs[row * 64 + (slot ^ (row & 7)) * 8]) = v;
    }
    if (tid < 64) { mrow[tid] = -1e30f; lrow[tid] = 0.f; }

    f32x4 oc[4];
#pragma unroll
    for (int j = 0; j < 4; ++j) oc[j] = (f32x4){0.f, 0.f, 0.f, 0.f};
    __syncthreads();

    for (int k0 = 0; k0 < T_SEQ; k0 += 64) {
        // stage K (bf16 convert) and Vt (already bf16)
#pragma unroll
        for (int it = 0; it < 2; ++it) {
            int s = it * 256 + tid;
            int row = s >> 3, slot = s & 7;
            const float* src = &qkvi[(size_t)(k0 + row) * QKVI_N + 1024 + kvh * HD + slot * 8];
            float4 a = *reinterpret_cast<const float4*>(src);
            float4 b = *reinterpret_cast<const float4*>(src + 4);
            bf16x8 v;
            v[0] = (bf16_t)a.x; v[1] = (bf16_t)a.y; v[2] = (bf16_t)a.z; v[3] = (bf16_t)a.w;
            v[4] = (bf16_t)b.x; v[5] = (bf16_t)b.y; v[6] = (bf16_t)b.z; v[7] = (bf16_t)b.w;
            *reinterpret_cast<bf16x8*>(&Ks[row * 64 + (slot ^ (row & 7)) * 8]) = v;
            *reinterpret_cast<bf16x8*>(&Vts[row * 64 + (slot ^ (row & 7)) * 8]) =
                *reinterpret_cast<const bf16x8*>(&Vtg[(size_t)(kvh * HD + row) * T_SEQ + k0 + slot * 8]);
        }
        __syncthreads();

        // QK^T: wave's 16 q-rows x 64 keys
        f32x4 sacc[4];
#pragma unroll
        for (int j = 0; j < 4; ++j) sacc[j] = (f32x4){0.f, 0.f, 0.f, 0.f};
#pragma unroll
        for (int kc = 0; kc < 2; ++kc) {
            int arow_ = wid * 16 + fr;
            bf16x8 aq = *reinterpret_cast<const bf16x8*>(&Qs[arow_ * 64 + (((kc * 4 + fq) ^ (arow_ & 7))) * 8]);
#pragma unroll
            for (int jb = 0; jb < 4; ++jb) {
                int brow = jb * 16 + fr;
                bf16x8 bk = *reinterpret_cast<const bf16x8*>(&Ks[brow * 64 + (((kc * 4 + fq) ^ (brow & 7))) * 8]);
                sacc[jb] = __builtin_amdgcn_mfma_f32_16x16x32_bf16(aq, bk, sacc[jb], 0, 0, 0);
            }
        }
        // bias + write S to LDS (fp32)
#pragma unroll
        for (int jb = 0; jb < 4; ++jb)
#pragma unroll
            for (int r = 0; r < 4; ++r) {
                int qq = q0 + wid * 16 + fq * 4 + r;
                int kk = k0 + jb * 16 + fr;
                float bias;
                if (kk == qq) bias = 0.f;
                else if (kk > qq) bias = LOGEPS;
                else if (qq < SELQ0) bias = 0.f;
                else bias = ((selmask[(size_t)qq * MASKW + (kk >> 5)] >> (kk & 31)) & 1u) ? 0.f : LOGEPS;
                Sb[wid * 16 + fq * 4 + r][jb * 16 + fr] = sacc[jb][r] + bias;
            }
        __syncthreads();

        // online softmax (audited block, 64 cols): 4 threads per row
        {
            int r = tid >> 2, ln = tid & 3;
            float mx = -1e30f;
#pragma unroll
            for (int c = 0; c < 16; ++c) mx = fmaxf(mx, Sb[r][ln * 16 + c]);
            mx = fmaxf(mx, __shfl_xor(mx, 1, 64));
            mx = fmaxf(mx, __shfl_xor(mx, 2, 64));
            float mnew = fmaxf(mrow[r], mx);
            float ssum = 0.f;
#pragma unroll
            for (int c = 0; c < 16; ++c) {
                float p = __expf(Sb[r][ln * 16 + c] - mnew);
                Sb[r][ln * 16 + c] = p;
                ssum += p;
            }
            ssum += __shfl_xor(ssum, 1, 64);
            ssum += __shfl_xor(ssum, 2, 64);
            if (ln == 0) {
                float a = __expf(mrow[r] - mnew);
                lrow[r] = lrow[r] * a + ssum;
                mrow[r] = mnew;
                arow[r] = a;
            }
        }
        __syncthreads();

        // rescale O, then PV
#pragma unroll
        for (int r = 0; r < 4; ++r) {
            float a = arow[wid * 16 + fq * 4 + r];
#pragma unroll
            for (int jb = 0; jb < 4; ++jb) oc[jb][r] *= a;
        }
#pragma unroll
        for (int kc = 0; kc < 2; ++kc) {
            const float* ps = &Sb[wid * 16 + fr][kc * 32 + fq * 8];
            float4 p0 = *reinterpret_cast<const float4*>(ps);
            float4 p1 = *reinterpret_cast<const float4*>(ps + 4);
            bf16x8 ap;
            ap[0] = (bf16_t)p0.x; ap[1] = (bf16_t)p0.y; ap[2] = (bf16_t)p0.z; ap[3] = (bf16_t)p0.w;
            ap[4] = (bf16_t)p1.x; ap[5] = (bf16_t)p1.y; ap[6] = (bf16_t)p1.z; ap[7] = (bf16_t)p1.w;
#pragma unroll
            for (int jb = 0; jb < 4; ++jb) {
                int brow = jb * 16 + fr;   // d-row of Vts
                bf16x8 bv = *reinterpret_cast<const bf16x8*>(&Vts[brow * 64 + (((kc * 4 + fq) ^ (brow & 7))) * 8]);
                oc[jb] = __builtin_amdgcn_mfma_f32_16x16x32_bf16(ap, bv, oc[jb], 0, 0, 0);
            }
        }
        __syncthreads();
    }

    // epilogue: divide by lrow, write y
#pragma unroll
    for (int r = 0; r < 4; ++r) {
        int rowl = wid * 16 + fq * 4 + r;
        float inv = 1.0f / lrow[rowl];
#pragma unroll
        for (int jb = 0; jb < 4; ++jb)
            yb[(size_t)(q0 + rowl) * C_DIM + h * HD + jb * 16 + fr] = oc[jb][r] * inv;
    }
}

// ---------------------------------------------------------------------------
extern "C" void kernel_launch(void* const* d_in, const int* in_sizes, int n_in,
                              void* d_out, int out_size, void* d_ws, size_t ws_size,
                              hipStream_t stream) {
    const float* x    = (const float*)d_in[0];
    const float* cosb = (const float*)d_in[1];
    const float* sinb = (const float*)d_in[2];
    const float* Wq   = (const float*)d_in[3];
    const float* Wk   = (const float*)d_in[4];
    const float* Wv   = (const float*)d_in[5];
    const float* Wo   = (const float*)d_in[6];
    const float* Wiq  = (const float*)d_in[7];
    const float* Wik  = (const float*)d_in[8];
    const float* Wiw  = (const float*)d_in[9];
    float* out = (float*)d_out;

    // ---- workspace carve (bytes) ----
    char* cur = (char*)d_ws;
    auto carve = [&](size_t bytes) { char* p = cur; cur += (bytes + 255) & ~(size_t)255; return p; };
    float*    qkvi  = (float*)   carve((size_t)T_SEQ * QKVI_N * 4);       // 25.2 MB
    float*    yb    = (float*)   carve((size_t)T_SEQ * C_DIM * 4);        // 12.6 MB
    float*    ikb   = (float*)   carve((size_t)T_SEQ * DI * 4);
    float*    iwb   = (float*)   carve((size_t)T_SEQ * HI * 4);
    unsigned* selm  = (unsigned*)carve((size_t)T_SEQ * MASKW * 4);
    bf16_t*   Wtp   = (bf16_t*)  carve((size_t)QKVI_N * C_DIM * 2);       // 4.2 MB
    bf16_t*   Wot   = (bf16_t*)  carve((size_t)C_DIM * C_DIM * 2);       // 2.1 MB
    bf16_t*   Vtg   = (bf16_t*)  carve((size_t)NKV * HD * T_SEQ * 2);    // 1.5 MB
    if ((size_t)(cur - (char*)d_ws) > ws_size) return;  // clean failure, not OOB

    dim3 blk(256);

    // 1. weights -> transposed bf16
    transp_conv<<<dim3(16, 16), blk, 0, stream>>>(Wq,  Wtp + (size_t)0    * 1024, 1024);
    transp_conv<<<dim3(4, 16),  blk, 0, stream>>>(Wk,  Wtp + (size_t)1024 * 1024, 256);
    transp_conv<<<dim3(4, 16),  blk, 0, stream>>>(Wv,  Wtp + (size_t)1280 * 1024, 256);
    transp_conv<<<dim3(8, 16),  blk, 0, stream>>>(Wiq, Wtp + (size_t)1536 * 1024, 512);
    transp_conv<<<dim3(16, 16), blk, 0, stream>>>(Wo,  Wot, 1024);

    // 2. fused projection GEMM (q|k|v|iq) via MFMA, fp32 A converted in staging
    gemm_mfma_t<true><<<dim3(QKVI_N / 128, T_SEQ / 128), blk, 0, stream>>>(x, Wtp, qkvi, QKVI_N);
    gemm_f32<<<dim3(1, 24), blk, 0, stream>>>(x, Wik, ikb, DI);
    gemm_f32<<<dim3(1, 24), blk, 0, stream>>>(x, Wiw, iwb, HI);

    // 3. RoPE + RMS on q/k in place; V transpose to bf16 [d][t]
    rope_rms<<<(T_SEQ * NH + 255) / 256, blk, 0, stream>>>(qkvi, cosb, sinb, NH, QKVI_N, 0);
    rope_rms<<<(T_SEQ * NKV + 255) / 256, blk, 0, stream>>>(qkvi, cosb, sinb, NKV, QKVI_N, 1024);
    transp_v<<<dim3(T_SEQ / 64, NKV), blk, 0, stream>>>(qkvi, Vtg);

    // 4. top-R selection masks
    imp_select<<<T_SEQ - SELQ0, blk, 0, stream>>>(qkvi, ikb, iwb, selm);

    // 5. MFMA attention
    attn_mfma<<<dim3(T_SEQ / 64, NH), blk, 0, stream>>>(qkvi, Vtg, selm, yb);

    // 6. output projection via MFMA (fp32 A converted in staging)
    gemm_mfma_t<true><<<dim3(C_DIM / 128, T_SEQ / 128), blk, 0, stream>>>(yb, Wot, out, C_DIM);
}

// Round 11
// 516.986 us; speedup vs baseline: 2.4538x; 2.4538x over previous
//
#include <hip/hip_runtime.h>
#include <hip/hip_bf16.h>
#include <math.h>

#define T_SEQ   3072
#define C_DIM   1024
#define NH      16
#define NKV     4
#define HD      64
#define HI      16
#define DI      32
#define LOCAL_W 128
#define TOPK    1536
#define SELQ0   (TOPK - LOCAL_W + 1)   /* 1409 */
#define RMS_EPS 1.1920929e-07f
#define LOGEPS  -13.815510558f
#define SCALE   0.125f
#define MASKW   (T_SEQ / 32)
#define QKVI_N  2176                   /* q(1024)|k(256)|v(256)|iq(512)|ik(32)|iw(16)|pad(80) */
#define IQ_OFF  1536
#define IK_OFF  2048
#define IW_OFF  2080

typedef __bf16 bf16_t;
typedef __bf16 bf16x8 __attribute__((ext_vector_type(8)));
typedef float  f32x4  __attribute__((ext_vector_type(4)));

// ---------------------------------------------------------------------------
// W[K=1024][N] fp32 -> Wt[N][1024] bf16 (transpose+convert), 64x64 tiles, N%64==0
// ---------------------------------------------------------------------------
__global__ __launch_bounds__(256) void transp_conv(const float* __restrict__ W,
                                                   bf16_t* __restrict__ Wt, int N) {
    __shared__ float t[64][65];
    int n0 = blockIdx.x * 64, k0 = blockIdx.y * 64;
#pragma unroll
    for (int it = 0; it < 16; ++it) {
        int flat = it * 256 + threadIdx.x;
        int i = flat >> 6, j = flat & 63;
        t[i][j] = W[(size_t)(k0 + i) * N + n0 + j];
    }
    __syncthreads();
#pragma unroll
    for (int it = 0; it < 16; ++it) {
        int flat = it * 256 + threadIdx.x;
        int n = flat >> 6, kk = flat & 63;
        Wt[(size_t)(n0 + n) * 1024 + k0 + kk] = (bf16_t)t[kk][n];
    }
}

// Guarded variant for skinny N (<64): reads padded with 0, writes only n<N rows.
__global__ __launch_bounds__(256) void transp_conv_g(const float* __restrict__ W,
                                                     bf16_t* __restrict__ Wt, int N) {
    __shared__ float t[64][65];
    int k0 = blockIdx.y * 64;
#pragma unroll
    for (int it = 0; it < 16; ++it) {
        int flat = it * 256 + threadIdx.x;
        int i = flat >> 6, j = flat & 63;
        t[i][j] = (j < N) ? W[(size_t)(k0 + i) * N + j] : 0.f;
    }
    __syncthreads();
#pragma unroll
    for (int it = 0; it < 16; ++it) {
        int flat = it * 256 + threadIdx.x;
        int n = flat >> 6, kk = flat & 63;
        if (n < N) Wt[(size_t)n * 1024 + k0 + kk] = (bf16_t)t[kk][n];
    }
}

// ---------------------------------------------------------------------------
// V region of qkvi (fp32 [t][1280 + kvh*64 + d]) -> Vtg bf16 [kvh*64+d][T]
// ---------------------------------------------------------------------------
__global__ __launch_bounds__(256) void transp_v(const float* __restrict__ qkvi,
                                                bf16_t* __restrict__ Vtg) {
    __shared__ float t[64][65];
    int t0 = blockIdx.x * 64, kvh = blockIdx.y;
#pragma unroll
    for (int it = 0; it < 16; ++it) {
        int flat = it * 256 + threadIdx.x;
        int i = flat >> 6, j = flat & 63;
        t[i][j] = qkvi[(size_t)(t0 + i) * QKVI_N + 1280 + kvh * HD + j];
    }
    __syncthreads();
#pragma unroll
    for (int it = 0; it < 16; ++it) {
        int flat = it * 256 + threadIdx.x;
        int dd = flat >> 6, tt = flat & 63;
        Vtg[(size_t)(kvh * HD + dd) * T_SEQ + t0 + tt] = (bf16_t)t[tt][dd];
    }
}

// ---------------------------------------------------------------------------
// bf16 MFMA GEMM: C[M][N] = A[M][1024] @ Bt[N][1024]^T, fp32 out.
// A_F32: A is fp32, converted during LDS staging. 128x128 tile, BK=64,
// 4 waves (2x2), wave tile 64x64, 16x16x32 MFMA, XOR-swizzled LDS.
// ---------------------------------------------------------------------------
template<bool A_F32>
__global__ __launch_bounds__(256) void gemm_mfma_t(const void* __restrict__ Ap,
                                                   const bf16_t* __restrict__ Bt,
                                                   float* __restrict__ C, int N) {
    __shared__ __align__(16) bf16_t As[128 * 64];
    __shared__ __align__(16) bf16_t Bs[128 * 64];
    const int tid = threadIdx.x;
    const int m0 = blockIdx.y * 128, n0 = blockIdx.x * 128;
    const int wid = tid >> 6, lane = tid & 63;
    const int wr = wid >> 1, wc = wid & 1;
    const int fr = lane & 15, fq = lane >> 4;

    f32x4 acc[4][4];
#pragma unroll
    for (int i = 0; i < 4; ++i)
#pragma unroll
        for (int j = 0; j < 4; ++j) acc[i][j] = (f32x4){0.f, 0.f, 0.f, 0.f};

    for (int k0 = 0; k0 < 1024; k0 += 64) {
        __syncthreads();
#pragma unroll
        for (int s = tid; s < 1024; s += 256) {
            int row = s >> 3, slot = s & 7;
            int sw = slot ^ (row & 7);
            bf16x8 av;
            if constexpr (A_F32) {
                const float* A = (const float*)Ap;
                const float* src = &A[(size_t)(m0 + row) * 1024 + k0 + slot * 8];
                float4 a = *reinterpret_cast<const float4*>(src);
                float4 b = *reinterpret_cast<const float4*>(src + 4);
                av[0] = (bf16_t)a.x; av[1] = (bf16_t)a.y; av[2] = (bf16_t)a.z; av[3] = (bf16_t)a.w;
                av[4] = (bf16_t)b.x; av[5] = (bf16_t)b.y; av[6] = (bf16_t)b.z; av[7] = (bf16_t)b.w;
            } else {
                const bf16_t* A = (const bf16_t*)Ap;
                av = *reinterpret_cast<const bf16x8*>(&A[(size_t)(m0 + row) * 1024 + k0 + slot * 8]);
            }
            *reinterpret_cast<bf16x8*>(&As[row * 64 + sw * 8]) = av;
            bf16x8 bv = *reinterpret_cast<const bf16x8*>(&Bt[(size_t)(n0 + row) * 1024 + k0 + slot * 8]);
            *reinterpret_cast<bf16x8*>(&Bs[row * 64 + sw * 8]) = bv;
        }
        __syncthreads();
#pragma unroll
        for (int kk = 0; kk < 2; ++kk) {
            bf16x8 af[4], bfr[4];
#pragma unroll
            for (int i = 0; i < 4; ++i) {
                int arow = wr * 64 + i * 16 + fr;
                int aslot = (kk * 4 + fq) ^ (arow & 7);
                af[i] = *reinterpret_cast<const bf16x8*>(&As[arow * 64 + aslot * 8]);
                int brow = wc * 64 + i * 16 + fr;
                int bslot = (kk * 4 + fq) ^ (brow & 7);
                bfr[i] = *reinterpret_cast<const bf16x8*>(&Bs[brow * 64 + bslot * 8]);
            }
#pragma unroll
            for (int i = 0; i < 4; ++i)
#pragma unroll
                for (int j = 0; j < 4; ++j)
                    acc[i][j] = __builtin_amdgcn_mfma_f32_16x16x32_bf16(af[i], bfr[j], acc[i][j], 0, 0, 0);
        }
    }
#pragma unroll
    for (int i = 0; i < 4; ++i)
#pragma unroll
        for (int j = 0; j < 4; ++j)
#pragma unroll
            for (int r = 0; r < 4; ++r) {
                int row = m0 + wr * 64 + i * 16 + fq * 4 + r;
                int col = n0 + wc * 64 + j * 16 + fr;
                C[(size_t)row * N + col] = acc[i][j][r];
            }
}

// ---------------------------------------------------------------------------
// RoPE + RMS norm, in place, strided fused-buffer layout.
// ---------------------------------------------------------------------------
__global__ __launch_bounds__(256) void rope_rms(float* __restrict__ data,
                                                const float* __restrict__ cosb,
                                                const float* __restrict__ sinb,
                                                int nheads, int rowstride, int coloff) {
    int idx = blockIdx.x * blockDim.x + threadIdx.x;
    if (idx >= T_SEQ * nheads) return;
    int t = idx / nheads, hh = idx % nheads;
    float* p = data + (size_t)t * rowstride + coloff + hh * HD;
    float o[HD];
    float ss = 0.f;
#pragma unroll
    for (int d = 0; d < 32; ++d) {
        float x1 = p[d], x2 = p[d + 32];
        float c = cosb[t * 32 + d], s = sinb[t * 32 + d];
        float a = x1 * c + x2 * s;
        float b = x2 * c - x1 * s;
        o[d] = a; o[d + 32] = b;
        ss += a * a + b * b;
    }
    float r = 1.0f / sqrtf(ss * (1.0f / HD) + RMS_EPS);
#pragma unroll
    for (int d = 0; d < HD; ++d) p[d] = o[d] * r;
}

// ---------------------------------------------------------------------------
// Importance scores via MFMA + exact top-R radix select, rows q in [SELQ0,T).
// Scores: one 16x16x32 MFMA per 16 keys (A=ik keys, B=iq heads, K=32=DI),
// relu+iw weight in-register, shfl_xor butterfly over the 16 head-lanes.
// Radix: 4x8-bit passes, per-pass parallel suffix-scan of the 256-bin hist.
// Tie-break lowest-index (jax.lax.top_k stability). Output: bitmask.
// ---------------------------------------------------------------------------
__global__ __launch_bounds__(256) void imp_select(const float* __restrict__ qkvi,
                                                  unsigned* __restrict__ selmask) {
    const int q = SELQ0 + blockIdx.x;
    const int tid = threadIdx.x;
    const int wid = tid >> 6, lane = tid & 63;
    const int fr = lane & 15, fq = lane >> 4;

    __shared__ unsigned keys[T_SEQ];
    __shared__ unsigned hist[256];
    __shared__ int sufx[257];
    __shared__ unsigned gtw[MASKW], eqw[MASKW];
    __shared__ int s_digit, s_need;

    // iq B-fragment: col(head)=fr, k=fq*8+j ; iw weight for this lane's head
    const float* iqp = &qkvi[(size_t)q * QKVI_N + IQ_OFF + fr * DI + fq * 8];
    float4 qa = *reinterpret_cast<const float4*>(iqp);
    float4 qb = *reinterpret_cast<const float4*>(iqp + 4);
    bf16x8 bq;
    bq[0] = (bf16_t)qa.x; bq[1] = (bf16_t)qa.y; bq[2] = (bf16_t)qa.z; bq[3] = (bf16_t)qa.w;
    bq[4] = (bf16_t)qb.x; bq[5] = (bf16_t)qb.y; bq[6] = (bf16_t)qb.z; bq[7] = (bf16_t)qb.w;
    const float wh = qkvi[(size_t)q * QKVI_N + IW_OFF + fr];

    // score phase: each wave covers 16 keys per 64-key tile
    for (int k0 = 0; k0 < q; k0 += 64) {
        int krow = k0 + wid * 16 + fr;        // A row (key); always < T_SEQ
        const float* ikp = &qkvi[(size_t)krow * QKVI_N + IK_OFF + fq * 8];
        float4 a = *reinterpret_cast<const float4*>(ikp);
        float4 b = *reinterpret_cast<const float4*>(ikp + 4);
        bf16x8 ak;
        ak[0] = (bf16_t)a.x; ak[1] = (bf16_t)a.y; ak[2] = (bf16_t)a.z; ak[3] = (bf16_t)a.w;
        ak[4] = (bf16_t)b.x; ak[5] = (bf16_t)b.y; ak[6] = (bf16_t)b.z; ak[7] = (bf16_t)b.w;
        f32x4 c = (f32x4){0.f, 0.f, 0.f, 0.f};
        c = __builtin_amdgcn_mfma_f32_16x16x32_bf16(ak, bq, c, 0, 0, 0);
        // weighted relu, then sum over head lanes (fr = bits 0..3 of lane id)
        float p0 = wh * fmaxf(c[0], 0.f);
        float p1 = wh * fmaxf(c[1], 0.f);
        float p2 = wh * fmaxf(c[2], 0.f);
        float p3 = wh * fmaxf(c[3], 0.f);
#pragma unroll
        for (int m = 1; m < 16; m <<= 1) {
            p0 += __shfl_xor(p0, m);
            p1 += __shfl_xor(p1, m);
            p2 += __shfl_xor(p2, m);
            p3 += __shfl_xor(p3, m);
        }
        if (fr == 0) {
            int kb = k0 + wid * 16 + fq * 4;
            float pv[4] = {p0, p1, p2, p3};
#pragma unroll
            for (int r = 0; r < 4; ++r) {
                int k = kb + r;
                if (k < q) {
                    unsigned u = __float_as_uint(pv[r]);
                    keys[k] = (u & 0x80000000u) ? ~u : (u | 0x80000000u);
                }
            }
        }
    }
    __syncthreads();

    const int F = min(LOCAL_W, T_SEQ - q);
    int need = TOPK - F;
    unsigned pref = 0;
    for (int b = 3; b >= 0; --b) {
        hist[tid] = 0;
        __syncthreads();
        unsigned above = (b == 3) ? 0u : (~0u << ((b + 1) * 8));
        for (int k = tid; k < q; k += 256) {
            unsigned key = keys[k];
            if ((key & above) == (pref & above))
                atomicAdd(&hist[(key >> (b * 8)) & 255u], 1u);
        }
        __syncthreads();
        // parallel suffix sum: sufx[t] = sum_{j>=t} hist[j]
        sufx[tid] = (int)hist[tid];
        if (tid == 0) sufx[256] = 0;
        __syncthreads();
        for (int s = 1; s < 256; s <<= 1) {
            int v = sufx[tid] + ((tid + s < 256) ? sufx[tid + s] : 0);
            __syncthreads();
            sufx[tid] = v;
            __syncthreads();
        }
        int nxt = sufx[tid + 1];
        if (sufx[tid] >= need && nxt < need) { s_digit = tid; s_need = need - nxt; }
        __syncthreads();
        pref |= ((unsigned)s_digit) << (b * 8);
        need = s_need;
        __syncthreads();
    }
    const unsigned V = pref;
    const int slots = need;   // # of ==V entries to take, lowest index first

    for (int w = tid; w < MASKW; w += 256) {
        unsigned g = 0, e = 0;
        int kbase = w * 32;
#pragma unroll 4
        for (int bit = 0; bit < 32; ++bit) {
            int k = kbase + bit;
            if (k < q) {
                unsigned key = keys[k];
                if (key > V) g |= (1u << bit);
                else if (key == V) e |= (1u << bit);
            }
        }
        gtw[w] = g; eqw[w] = e;
    }
    __syncthreads();
    if (tid == 0) {
        int rem = slots;
        for (int w = 0; w < MASKW && rem > 0; ++w) {
            unsigned e = eqw[w];
            if (!e) continue;
            int pc = __popc(e);
            if (pc <= rem) { gtw[w] |= e; rem -= pc; }
            else {
                unsigned sel = 0;
                for (int i = 0; i < rem; ++i) { unsigned lb = e & (~e + 1u); sel |= lb; e ^= lb; }
                gtw[w] |= sel; rem = 0;
            }
        }
    }
    __syncthreads();
    for (int w = tid; w < MASKW; w += 256) selmask[(size_t)q * MASKW + w] = gtw[w];
}

// ---------------------------------------------------------------------------
// MFMA attention: one block per (64-q-tile, head), 4 waves, KT=64 key tiles.
// QK^T and PV via 16x16x32 bf16 MFMA; bias + online softmax fp32 via Sb LDS.
// ---------------------------------------------------------------------------
__global__ __launch_bounds__(256) void attn_mfma(const float* __restrict__ qkvi,
                                                 const bf16_t* __restrict__ Vtg,
                                                 const unsigned* __restrict__ selmask,
                                                 float* __restrict__ yb) {
    const int q0 = blockIdx.x * 64;
    const int h = blockIdx.y;
    const int kvh = h >> 2;
    const int tid = threadIdx.x;
    const int wid = tid >> 6, lane = tid & 63;
    const int fr = lane & 15, fq = lane >> 4;

    __shared__ __align__(16) bf16_t Qs[64 * 64];
    __shared__ __align__(16) bf16_t Ks[64 * 64];
    __shared__ __align__(16) bf16_t Vts[64 * 64];   // [d][key]
    __shared__ __align__(16) float Sb[64][68];
    __shared__ float mrow[64], lrow[64], arow[64];

#pragma unroll
    for (int it = 0; it < 2; ++it) {
        int s = it * 256 + tid;
        int row = s >> 3, slot = s & 7;
        const float* src = &qkvi[(size_t)(q0 + row) * QKVI_N + h * HD + slot * 8];
        float4 a = *reinterpret_cast<const float4*>(src);
        float4 b = *reinterpret_cast<const float4*>(src + 4);
        bf16x8 v;
        v[0] = (bf16_t)(a.x * SCALE); v[1] = (bf16_t)(a.y * SCALE);
        v[2] = (bf16_t)(a.z * SCALE); v[3] = (bf16_t)(a.w * SCALE);
        v[4] = (bf16_t)(b.x * SCALE); v[5] = (bf16_t)(b.y * SCALE);
        v[6] = (bf16_t)(b.z * SCALE); v[7] = (bf16_t)(b.w * SCALE);
        *reinterpret_cast<bf16x8*>(&Qs[row * 64 + (slot ^ (row & 7)) * 8]) = v;
    }
    if (tid < 64) { mrow[tid] = -1e30f; lrow[tid] = 0.f; }

    f32x4 oc[4];
#pragma unroll
    for (int j = 0; j < 4; ++j) oc[j] = (f32x4){0.f, 0.f, 0.f, 0.f};
    __syncthreads();

    for (int k0 = 0; k0 < T_SEQ; k0 += 64) {
#pragma unroll
        for (int it = 0; it < 2; ++it) {
            int s = it * 256 + tid;
            int row = s >> 3, slot = s & 7;
            const float* src = &qkvi[(size_t)(k0 + row) * QKVI_N + 1024 + kvh * HD + slot * 8];
            float4 a = *reinterpret_cast<const float4*>(src);
            float4 b = *reinterpret_cast<const float4*>(src + 4);
            bf16x8 v;
            v[0] = (bf16_t)a.x; v[1] = (bf16_t)a.y; v[2] = (bf16_t)a.z; v[3] = (bf16_t)a.w;
            v[4] = (bf16_t)b.x; v[5] = (bf16_t)b.y; v[6] = (bf16_t)b.z; v[7] = (bf16_t)b.w;
            *reinterpret_cast<bf16x8*>(&Ks[row * 64 + (slot ^ (row & 7)) * 8]) = v;
            *reinterpret_cast<bf16x8*>(&Vts[row * 64 + (slot ^ (row & 7)) * 8]) =
                *reinterpret_cast<const bf16x8*>(&Vtg[(size_t)(kvh * HD + row) * T_SEQ + k0 + slot * 8]);
        }
        __syncthreads();

        f32x4 sacc[4];
#pragma unroll
        for (int j = 0; j < 4; ++j) sacc[j] = (f32x4){0.f, 0.f, 0.f, 0.f};
#pragma unroll
        for (int kc = 0; kc < 2; ++kc) {
            int arow_ = wid * 16 + fr;
            bf16x8 aq = *reinterpret_cast<const bf16x8*>(&Qs[arow_ * 64 + (((kc * 4 + fq) ^ (arow_ & 7))) * 8]);
#pragma unroll
            for (int jb = 0; jb < 4; ++jb) {
                int brow = jb * 16 + fr;
                bf16x8 bk = *reinterpret_cast<const bf16x8*>(&Ks[brow * 64 + (((kc * 4 + fq) ^ (brow & 7))) * 8]);
                sacc[jb] = __builtin_amdgcn_mfma_f32_16x16x32_bf16(aq, bk, sacc[jb], 0, 0, 0);
            }
        }
#pragma unroll
        for (int jb = 0; jb < 4; ++jb)
#pragma unroll
            for (int r = 0; r < 4; ++r) {
                int qq = q0 + wid * 16 + fq * 4 + r;
                int kk = k0 + jb * 16 + fr;
                float bias;
                if (kk == qq) bias = 0.f;
                else if (kk > qq) bias = LOGEPS;
                else if (qq < SELQ0) bias = 0.f;
                else bias = ((selmask[(size_t)qq * MASKW + (kk >> 5)] >> (kk & 31)) & 1u) ? 0.f : LOGEPS;
                Sb[wid * 16 + fq * 4 + r][jb * 16 + fr] = sacc[jb][r] + bias;
            }
        __syncthreads();

        {
            int r = tid >> 2, ln = tid & 3;
            float mx = -1e30f;
#pragma unroll
            for (int c = 0; c < 16; ++c) mx = fmaxf(mx, Sb[r][ln * 16 + c]);
            mx = fmaxf(mx, __shfl_xor(mx, 1, 64));
            mx = fmaxf(mx, __shfl_xor(mx, 2, 64));
            float mnew = fmaxf(mrow[r], mx);
            float ssum = 0.f;
#pragma unroll
            for (int c = 0; c < 16; ++c) {
                float p = __expf(Sb[r][ln * 16 + c] - mnew);
                Sb[r][ln * 16 + c] = p;
                ssum += p;
            }
            ssum += __shfl_xor(ssum, 1, 64);
            ssum += __shfl_xor(ssum, 2, 64);
            if (ln == 0) {
                float a = __expf(mrow[r] - mnew);
                lrow[r] = lrow[r] * a + ssum;
                mrow[r] = mnew;
                arow[r] = a;
            }
        }
        __syncthreads();

#pragma unroll
        for (int r = 0; r < 4; ++r) {
            float a = arow[wid * 16 + fq * 4 + r];
#pragma unroll
            for (int jb = 0; jb < 4; ++jb) oc[jb][r] *= a;
        }
#pragma unroll
        for (int kc = 0; kc < 2; ++kc) {
            const float* ps = &Sb[wid * 16 + fr][kc * 32 + fq * 8];
            float4 p0 = *reinterpret_cast<const float4*>(ps);
            float4 p1 = *reinterpret_cast<const float4*>(ps + 4);
            bf16x8 ap;
            ap[0] = (bf16_t)p0.x; ap[1] = (bf16_t)p0.y; ap[2] = (bf16_t)p0.z; ap[3] = (bf16_t)p0.w;
            ap[4] = (bf16_t)p1.x; ap[5] = (bf16_t)p1.y; ap[6] = (bf16_t)p1.z; ap[7] = (bf16_t)p1.w;
#pragma unroll
            for (int jb = 0; jb < 4; ++jb) {
                int brow = jb * 16 + fr;
                bf16x8 bv = *reinterpret_cast<const bf16x8*>(&Vts[brow * 64 + (((kc * 4 + fq) ^ (brow & 7))) * 8]);
                oc[jb] = __builtin_amdgcn_mfma_f32_16x16x32_bf16(ap, bv, oc[jb], 0, 0, 0);
            }
        }
        __syncthreads();
    }

#pragma unroll
    for (int r = 0; r < 4; ++r) {
        int rowl = wid * 16 + fq * 4 + r;
        float inv = 1.0f / lrow[rowl];
#pragma unroll
        for (int jb = 0; jb < 4; ++jb)
            yb[(size_t)(q0 + rowl) * C_DIM + h * HD + jb * 16 + fr] = oc[jb][r] * inv;
    }
}

// ---------------------------------------------------------------------------
extern "C" void kernel_launch(void* const* d_in, const int* in_sizes, int n_in,
                              void* d_out, int out_size, void* d_ws, size_t ws_size,
                              hipStream_t stream) {
    const float* x    = (const float*)d_in[0];
    const float* cosb = (const float*)d_in[1];
    const float* sinb = (const float*)d_in[2];
    const float* Wq   = (const float*)d_in[3];
    const float* Wk   = (const float*)d_in[4];
    const float* Wv   = (const float*)d_in[5];
    const float* Wo   = (const float*)d_in[6];
    const float* Wiq  = (const float*)d_in[7];
    const float* Wik  = (const float*)d_in[8];
    const float* Wiw  = (const float*)d_in[9];
    float* out = (float*)d_out;

    // ---- workspace carve (bytes) ----
    char* cur = (char*)d_ws;
    auto carve = [&](size_t bytes) { char* p = cur; cur += (bytes + 255) & ~(size_t)255; return p; };
    float*    qkvi  = (float*)   carve((size_t)T_SEQ * QKVI_N * 4);       // 26.7 MB
    float*    yb    = (float*)   carve((size_t)T_SEQ * C_DIM * 4);        // 12.6 MB
    unsigned* selm  = (unsigned*)carve((size_t)T_SEQ * MASKW * 4);        // 1.2 MB
    bf16_t*   Wtp   = (bf16_t*)  carve((size_t)QKVI_N * C_DIM * 2);       // 4.5 MB
    bf16_t*   Wot   = (bf16_t*)  carve((size_t)C_DIM * C_DIM * 2);        // 2.1 MB
    bf16_t*   Vtg   = (bf16_t*)  carve((size_t)NKV * HD * T_SEQ * 2);     // 1.5 MB
    if ((size_t)(cur - (char*)d_ws) > ws_size) return;  // clean failure, not OOB

    dim3 blk(256);

    // 1. weights -> transposed bf16 (rows of Wtp: q|k|v|iq|ik|iw|pad-garbage)
    transp_conv<<<dim3(16, 16), blk, 0, stream>>>(Wq,  Wtp + (size_t)0    * 1024, 1024);
    transp_conv<<<dim3(4, 16),  blk, 0, stream>>>(Wk,  Wtp + (size_t)1024 * 1024, 256);
    transp_conv<<<dim3(4, 16),  blk, 0, stream>>>(Wv,  Wtp + (size_t)1280 * 1024, 256);
    transp_conv<<<dim3(8, 16),  blk, 0, stream>>>(Wiq, Wtp + (size_t)IQ_OFF * 1024, 512);
    transp_conv_g<<<dim3(1, 16), blk, 0, stream>>>(Wik, Wtp + (size_t)IK_OFF * 1024, DI);
    transp_conv_g<<<dim3(1, 16), blk, 0, stream>>>(Wiw, Wtp + (size_t)IW_OFF * 1024, HI);
    transp_conv<<<dim3(16, 16), blk, 0, stream>>>(Wo,  Wot, 1024);

    // 2. fused projection GEMM (q|k|v|iq|ik|iw) via MFMA (pad cols confined)
    gemm_mfma_t<true><<<dim3(QKVI_N / 128, T_SEQ / 128), blk, 0, stream>>>(x, Wtp, qkvi, QKVI_N);

    // 3. RoPE + RMS on q/k in place; V transpose to bf16 [d][t]
    rope_rms<<<(T_SEQ * NH + 255) / 256, blk, 0, stream>>>(qkvi, cosb, sinb, NH, QKVI_N, 0);
    rope_rms<<<(T_SEQ * NKV + 255) / 256, blk, 0, stream>>>(qkvi, cosb, sinb, NKV, QKVI_N, 1024);
    transp_v<<<dim3(T_SEQ / 64, NKV), blk, 0, stream>>>(qkvi, Vtg);

    // 4. top-R selection masks (MFMA scores + radix select)
    imp_select<<<T_SEQ - SELQ0, blk, 0, stream>>>(qkvi, selm);

    // 5. MFMA attention
    attn_mfma<<<dim3(T_SEQ / 64, NH), blk, 0, stream>>>(qkvi, Vtg, selm, yb);

    // 6. output projection via MFMA
    gemm_mfma_t<true><<<dim3(C_DIM / 128, T_SEQ / 128), blk, 0, stream>>>(yb, Wot, out, C_DIM);
}

// Round 12
// 429.664 us; speedup vs baseline: 2.9525x; 1.2032x over previous
//
#include <hip/hip_runtime.h>
#include <hip/hip_bf16.h>
#include <math.h>

#define T_SEQ   3072
#define C_DIM   1024
#define NH      16
#define NKV     4
#define HD      64
#define HI      16
#define DI      32
#define LOCAL_W 128
#define TOPK    1536
#define SELQ0   (TOPK - LOCAL_W + 1)   /* 1409 */
#define RMS_EPS 1.1920929e-07f
#define LOGEPS  -13.815510558f
#define SCALE   0.125f
#define MASKW   (T_SEQ / 32)
#define QKVI_N  2176                   /* q(1024)|k(256)|v(256)|iq(512)|ik(32)|iw(16)|pad(80) */
#define IQ_OFF  1536
#define IK_OFF  2048
#define IW_OFF  2080

typedef __bf16 bf16_t;
typedef __bf16 bf16x8 __attribute__((ext_vector_type(8)));
typedef float  f32x4  __attribute__((ext_vector_type(4)));

// ---------------------------------------------------------------------------
// W[K=1024][N] fp32 -> Wt[N][1024] bf16 (transpose+convert), 64x64 tiles, N%64==0
// ---------------------------------------------------------------------------
__global__ __launch_bounds__(256) void transp_conv(const float* __restrict__ W,
                                                   bf16_t* __restrict__ Wt, int N) {
    __shared__ float t[64][65];
    int n0 = blockIdx.x * 64, k0 = blockIdx.y * 64;
#pragma unroll
    for (int it = 0; it < 16; ++it) {
        int flat = it * 256 + threadIdx.x;
        int i = flat >> 6, j = flat & 63;
        t[i][j] = W[(size_t)(k0 + i) * N + n0 + j];
    }
    __syncthreads();
#pragma unroll
    for (int it = 0; it < 16; ++it) {
        int flat = it * 256 + threadIdx.x;
        int n = flat >> 6, kk = flat & 63;
        Wt[(size_t)(n0 + n) * 1024 + k0 + kk] = (bf16_t)t[kk][n];
    }
}

// Guarded variant for skinny N (<64): reads padded with 0, writes only n<N rows.
__global__ __launch_bounds__(256) void transp_conv_g(const float* __restrict__ W,
                                                     bf16_t* __restrict__ Wt, int N) {
    __shared__ float t[64][65];
    int k0 = blockIdx.y * 64;
#pragma unroll
    for (int it = 0; it < 16; ++it) {
        int flat = it * 256 + threadIdx.x;
        int i = flat >> 6, j = flat & 63;
        t[i][j] = (j < N) ? W[(size_t)(k0 + i) * N + j] : 0.f;
    }
    __syncthreads();
#pragma unroll
    for (int it = 0; it < 16; ++it) {
        int flat = it * 256 + threadIdx.x;
        int n = flat >> 6, kk = flat & 63;
        if (n < N) Wt[(size_t)n * 1024 + k0 + kk] = (bf16_t)t[kk][n];
    }
}

// ---------------------------------------------------------------------------
// K region -> Kb bf16 [t][kvh*64+d] (row-major convert) and
// V region -> Vtg bf16 [kvh*64+d][T] (transpose). One block per (64 t, kvh).
// ---------------------------------------------------------------------------
__global__ __launch_bounds__(256) void pack_kv(const float* __restrict__ qkvi,
                                               bf16_t* __restrict__ Kb,
                                               bf16_t* __restrict__ Vtg) {
    __shared__ float t[64][65];
    int t0 = blockIdx.x * 64, kvh = blockIdx.y;
    // K: straight convert, coalesced both sides
#pragma unroll
    for (int it = 0; it < 2; ++it) {
        int s = it * 256 + threadIdx.x;
        int row = s >> 3, slot = s & 7;
        const float* src = &qkvi[(size_t)(t0 + row) * QKVI_N + 1024 + kvh * HD + slot * 8];
        float4 a = *reinterpret_cast<const float4*>(src);
        float4 b = *reinterpret_cast<const float4*>(src + 4);
        bf16x8 v;
        v[0] = (bf16_t)a.x; v[1] = (bf16_t)a.y; v[2] = (bf16_t)a.z; v[3] = (bf16_t)a.w;
        v[4] = (bf16_t)b.x; v[5] = (bf16_t)b.y; v[6] = (bf16_t)b.z; v[7] = (bf16_t)b.w;
        *reinterpret_cast<bf16x8*>(&Kb[(size_t)(t0 + row) * (NKV * HD) + kvh * HD + slot * 8]) = v;
    }
    // V: transpose via LDS
#pragma unroll
    for (int it = 0; it < 16; ++it) {
        int flat = it * 256 + threadIdx.x;
        int i = flat >> 6, j = flat & 63;
        t[i][j] = qkvi[(size_t)(t0 + i) * QKVI_N + 1280 + kvh * HD + j];
    }
    __syncthreads();
#pragma unroll
    for (int it = 0; it < 16; ++it) {
        int flat = it * 256 + threadIdx.x;
        int dd = flat >> 6, tt = flat & 63;
        Vtg[(size_t)(kvh * HD + dd) * T_SEQ + t0 + tt] = (bf16_t)t[tt][dd];
    }
}

// ---------------------------------------------------------------------------
// Bias bitmask for rows [0, SELQ0): bit k set (bias 0) iff k <= row (causal
// past + diagonal). Rows >= SELQ0 are written by imp_select.
// ---------------------------------------------------------------------------
__global__ __launch_bounds__(256) void causal_mask(unsigned* __restrict__ selm) {
    int idx = blockIdx.x * 256 + threadIdx.x;
    if (idx >= SELQ0 * MASKW) return;
    int row = idx / MASKW, w = idx % MASKW;
    int wq = row >> 5, b = row & 31;
    unsigned v;
    if (w < wq) v = ~0u;
    else if (w == wq) v = (b == 31) ? ~0u : ((1u << (b + 1)) - 1u);
    else v = 0u;
    selm[(size_t)row * MASKW + w] = v;
}

// ---------------------------------------------------------------------------
// bf16 MFMA GEMM: C[M][N] = A[M][1024] @ Bt[N][1024]^T, fp32 out.
// A_F32: A is fp32, converted during LDS staging. 128x128 tile, BK=64,
// 4 waves (2x2), wave tile 64x64, 16x16x32 MFMA, XOR-swizzled LDS.
// ---------------------------------------------------------------------------
template<bool A_F32>
__global__ __launch_bounds__(256) void gemm_mfma_t(const void* __restrict__ Ap,
                                                   const bf16_t* __restrict__ Bt,
                                                   float* __restrict__ C, int N) {
    __shared__ __align__(16) bf16_t As[128 * 64];
    __shared__ __align__(16) bf16_t Bs[128 * 64];
    const int tid = threadIdx.x;
    const int m0 = blockIdx.y * 128, n0 = blockIdx.x * 128;
    const int wid = tid >> 6, lane = tid & 63;
    const int wr = wid >> 1, wc = wid & 1;
    const int fr = lane & 15, fq = lane >> 4;

    f32x4 acc[4][4];
#pragma unroll
    for (int i = 0; i < 4; ++i)
#pragma unroll
        for (int j = 0; j < 4; ++j) acc[i][j] = (f32x4){0.f, 0.f, 0.f, 0.f};

    for (int k0 = 0; k0 < 1024; k0 += 64) {
        __syncthreads();
#pragma unroll
        for (int s = tid; s < 1024; s += 256) {
            int row = s >> 3, slot = s & 7;
            int sw = slot ^ (row & 7);
            bf16x8 av;
            if constexpr (A_F32) {
                const float* A = (const float*)Ap;
                const float* src = &A[(size_t)(m0 + row) * 1024 + k0 + slot * 8];
                float4 a = *reinterpret_cast<const float4*>(src);
                float4 b = *reinterpret_cast<const float4*>(src + 4);
                av[0] = (bf16_t)a.x; av[1] = (bf16_t)a.y; av[2] = (bf16_t)a.z; av[3] = (bf16_t)a.w;
                av[4] = (bf16_t)b.x; av[5] = (bf16_t)b.y; av[6] = (bf16_t)b.z; av[7] = (bf16_t)b.w;
            } else {
                const bf16_t* A = (const bf16_t*)Ap;
                av = *reinterpret_cast<const bf16x8*>(&A[(size_t)(m0 + row) * 1024 + k0 + slot * 8]);
            }
            *reinterpret_cast<bf16x8*>(&As[row * 64 + sw * 8]) = av;
            bf16x8 bv = *reinterpret_cast<const bf16x8*>(&Bt[(size_t)(n0 + row) * 1024 + k0 + slot * 8]);
            *reinterpret_cast<bf16x8*>(&Bs[row * 64 + sw * 8]) = bv;
        }
        __syncthreads();
#pragma unroll
        for (int kk = 0; kk < 2; ++kk) {
            bf16x8 af[4], bfr[4];
#pragma unroll
            for (int i = 0; i < 4; ++i) {
                int arow = wr * 64 + i * 16 + fr;
                int aslot = (kk * 4 + fq) ^ (arow & 7);
                af[i] = *reinterpret_cast<const bf16x8*>(&As[arow * 64 + aslot * 8]);
                int brow = wc * 64 + i * 16 + fr;
                int bslot = (kk * 4 + fq) ^ (brow & 7);
                bfr[i] = *reinterpret_cast<const bf16x8*>(&Bs[brow * 64 + bslot * 8]);
            }
#pragma unroll
            for (int i = 0; i < 4; ++i)
#pragma unroll
                for (int j = 0; j < 4; ++j)
                    acc[i][j] = __builtin_amdgcn_mfma_f32_16x16x32_bf16(af[i], bfr[j], acc[i][j], 0, 0, 0);
        }
    }
#pragma unroll
    for (int i = 0; i < 4; ++i)
#pragma unroll
        for (int j = 0; j < 4; ++j)
#pragma unroll
            for (int r = 0; r < 4; ++r) {
                int row = m0 + wr * 64 + i * 16 + fq * 4 + r;
                int col = n0 + wc * 64 + j * 16 + fr;
                C[(size_t)row * N + col] = acc[i][j][r];
            }
}

// ---------------------------------------------------------------------------
// RoPE + RMS norm, in place, strided fused-buffer layout.
// ---------------------------------------------------------------------------
__global__ __launch_bounds__(256) void rope_rms(float* __restrict__ data,
                                                const float* __restrict__ cosb,
                                                const float* __restrict__ sinb,
                                                int nheads, int rowstride, int coloff) {
    int idx = blockIdx.x * blockDim.x + threadIdx.x;
    if (idx >= T_SEQ * nheads) return;
    int t = idx / nheads, hh = idx % nheads;
    float* p = data + (size_t)t * rowstride + coloff + hh * HD;
    float o[HD];
    float ss = 0.f;
#pragma unroll
    for (int d = 0; d < 32; ++d) {
        float x1 = p[d], x2 = p[d + 32];
        float c = cosb[t * 32 + d], s = sinb[t * 32 + d];
        float a = x1 * c + x2 * s;
        float b = x2 * c - x1 * s;
        o[d] = a; o[d + 32] = b;
        ss += a * a + b * b;
    }
    float r = 1.0f / sqrtf(ss * (1.0f / HD) + RMS_EPS);
#pragma unroll
    for (int d = 0; d < HD; ++d) p[d] = o[d] * r;
}

// ---------------------------------------------------------------------------
// Importance scores via MFMA + exact top-R radix select, rows q in [SELQ0,T).
// Output mask includes the diagonal bit (bias-0 bit). Tie-break lowest-index.
// ---------------------------------------------------------------------------
__global__ __launch_bounds__(256) void imp_select(const float* __restrict__ qkvi,
                                                  unsigned* __restrict__ selmask) {
    const int q = SELQ0 + blockIdx.x;
    const int tid = threadIdx.x;
    const int wid = tid >> 6, lane = tid & 63;
    const int fr = lane & 15, fq = lane >> 4;

    __shared__ unsigned keys[T_SEQ];
    __shared__ unsigned hist[256];
    __shared__ int sufx[257];
    __shared__ unsigned gtw[MASKW], eqw[MASKW];
    __shared__ int s_digit, s_need;

    // iq B-fragment: col(head)=fr, k=fq*8+j ; iw weight for this lane's head
    const float* iqp = &qkvi[(size_t)q * QKVI_N + IQ_OFF + fr * DI + fq * 8];
    float4 qa = *reinterpret_cast<const float4*>(iqp);
    float4 qb = *reinterpret_cast<const float4*>(iqp + 4);
    bf16x8 bq;
    bq[0] = (bf16_t)qa.x; bq[1] = (bf16_t)qa.y; bq[2] = (bf16_t)qa.z; bq[3] = (bf16_t)qa.w;
    bq[4] = (bf16_t)qb.x; bq[5] = (bf16_t)qb.y; bq[6] = (bf16_t)qb.z; bq[7] = (bf16_t)qb.w;
    const float wh = qkvi[(size_t)q * QKVI_N + IW_OFF + fr];

    for (int k0 = 0; k0 < q; k0 += 64) {
        int krow = k0 + wid * 16 + fr;
        const float* ikp = &qkvi[(size_t)krow * QKVI_N + IK_OFF + fq * 8];
        float4 a = *reinterpret_cast<const float4*>(ikp);
        float4 b = *reinterpret_cast<const float4*>(ikp + 4);
        bf16x8 ak;
        ak[0] = (bf16_t)a.x; ak[1] = (bf16_t)a.y; ak[2] = (bf16_t)a.z; ak[3] = (bf16_t)a.w;
        ak[4] = (bf16_t)b.x; ak[5] = (bf16_t)b.y; ak[6] = (bf16_t)b.z; ak[7] = (bf16_t)b.w;
        f32x4 c = (f32x4){0.f, 0.f, 0.f, 0.f};
        c = __builtin_amdgcn_mfma_f32_16x16x32_bf16(ak, bq, c, 0, 0, 0);
        float p0 = wh * fmaxf(c[0], 0.f);
        float p1 = wh * fmaxf(c[1], 0.f);
        float p2 = wh * fmaxf(c[2], 0.f);
        float p3 = wh * fmaxf(c[3], 0.f);
#pragma unroll
        for (int m = 1; m < 16; m <<= 1) {
            p0 += __shfl_xor(p0, m);
            p1 += __shfl_xor(p1, m);
            p2 += __shfl_xor(p2, m);
            p3 += __shfl_xor(p3, m);
        }
        if (fr == 0) {
            int kb = k0 + wid * 16 + fq * 4;
            float pv[4] = {p0, p1, p2, p3};
#pragma unroll
            for (int r = 0; r < 4; ++r) {
                int k = kb + r;
                if (k < q) {
                    unsigned u = __float_as_uint(pv[r]);
                    keys[k] = (u & 0x80000000u) ? ~u : (u | 0x80000000u);
                }
            }
        }
    }
    __syncthreads();

    const int F = min(LOCAL_W, T_SEQ - q);
    int need = TOPK - F;
    unsigned pref = 0;
    for (int b = 3; b >= 0; --b) {
        hist[tid] = 0;
        __syncthreads();
        unsigned above = (b == 3) ? 0u : (~0u << ((b + 1) * 8));
        for (int k = tid; k < q; k += 256) {
            unsigned key = keys[k];
            if ((key & above) == (pref & above))
                atomicAdd(&hist[(key >> (b * 8)) & 255u], 1u);
        }
        __syncthreads();
        sufx[tid] = (int)hist[tid];
        if (tid == 0) sufx[256] = 0;
        __syncthreads();
        for (int s = 1; s < 256; s <<= 1) {
            int v = sufx[tid] + ((tid + s < 256) ? sufx[tid + s] : 0);
            __syncthreads();
            sufx[tid] = v;
            __syncthreads();
        }
        int nxt = sufx[tid + 1];
        if (sufx[tid] >= need && nxt < need) { s_digit = tid; s_need = need - nxt; }
        __syncthreads();
        pref |= ((unsigned)s_digit) << (b * 8);
        need = s_need;
        __syncthreads();
    }
    const unsigned V = pref;
    const int slots = need;

    for (int w = tid; w < MASKW; w += 256) {
        unsigned g = 0, e = 0;
        int kbase = w * 32;
#pragma unroll 4
        for (int bit = 0; bit < 32; ++bit) {
            int k = kbase + bit;
            if (k < q) {
                unsigned key = keys[k];
                if (key > V) g |= (1u << bit);
                else if (key == V) e |= (1u << bit);
            }
        }
        gtw[w] = g; eqw[w] = e;
    }
    __syncthreads();
    if (tid == 0) {
        int rem = slots;
        for (int w = 0; w < MASKW && rem > 0; ++w) {
            unsigned e = eqw[w];
            if (!e) continue;
            int pc = __popc(e);
            if (pc <= rem) { gtw[w] |= e; rem -= pc; }
            else {
                unsigned sel = 0;
                for (int i = 0; i < rem; ++i) { unsigned lb = e & (~e + 1u); sel |= lb; e ^= lb; }
                gtw[w] |= sel; rem = 0;
            }
        }
    }
    __syncthreads();
    for (int w = tid; w < MASKW; w += 256) {
        unsigned g = gtw[w];
        if (w == (q >> 5)) g |= (1u << (q & 31));   // diagonal: bias 0
        selmask[(size_t)q * MASKW + w] = g;
    }
}

// ---------------------------------------------------------------------------
// MFMA attention: one block per (64-q-tile, head), 4 waves, KT=64 key tiles.
// Branchless bias via precomputed bitmask staged per-tile into LDS.
// K staged from bf16 Kb; V from transposed bf16 Vtg. Softmax float4-vectorized.
// ---------------------------------------------------------------------------
__global__ __launch_bounds__(256) void attn_mfma(const float* __restrict__ qkvi,
                                                 const bf16_t* __restrict__ Kb,
                                                 const bf16_t* __restrict__ Vtg,
                                                 const unsigned* __restrict__ selmask,
                                                 float* __restrict__ yb) {
    const int q0 = blockIdx.x * 64;
    const int h = blockIdx.y;
    const int kvh = h >> 2;
    const int tid = threadIdx.x;
    const int wid = tid >> 6, lane = tid & 63;
    const int fr = lane & 15, fq = lane >> 4;

    __shared__ __align__(16) bf16_t Qs[64 * 64];
    __shared__ __align__(16) bf16_t Ks[64 * 64];
    __shared__ __align__(16) bf16_t Vts[64 * 64];   // [d][key]
    __shared__ __align__(16) float Sb[64][68];
    __shared__ unsigned mlds[64][2];
    __shared__ float mrow[64], lrow[64], arow[64];

#pragma unroll
    for (int it = 0; it < 2; ++it) {
        int s = it * 256 + tid;
        int row = s >> 3, slot = s & 7;
        const float* src = &qkvi[(size_t)(q0 + row) * QKVI_N + h * HD + slot * 8];
        float4 a = *reinterpret_cast<const float4*>(src);
        float4 b = *reinterpret_cast<const float4*>(src + 4);
        bf16x8 v;
        v[0] = (bf16_t)(a.x * SCALE); v[1] = (bf16_t)(a.y * SCALE);
        v[2] = (bf16_t)(a.z * SCALE); v[3] = (bf16_t)(a.w * SCALE);
        v[4] = (bf16_t)(b.x * SCALE); v[5] = (bf16_t)(b.y * SCALE);
        v[6] = (bf16_t)(b.z * SCALE); v[7] = (bf16_t)(b.w * SCALE);
        *reinterpret_cast<bf16x8*>(&Qs[row * 64 + (slot ^ (row & 7)) * 8]) = v;
    }
    if (tid < 64) { mrow[tid] = -1e30f; lrow[tid] = 0.f; }

    f32x4 oc[4];
#pragma unroll
    for (int j = 0; j < 4; ++j) oc[j] = (f32x4){0.f, 0.f, 0.f, 0.f};
    __syncthreads();

    for (int k0 = 0; k0 < T_SEQ; k0 += 64) {
        // stage K (bf16), Vt (bf16), and the 2 bias-mask words per q-row
#pragma unroll
        for (int it = 0; it < 2; ++it) {
            int s = it * 256 + tid;
            int row = s >> 3, slot = s & 7;
            *reinterpret_cast<bf16x8*>(&Ks[row * 64 + (slot ^ (row & 7)) * 8]) =
                *reinterpret_cast<const bf16x8*>(&Kb[(size_t)(k0 + row) * (NKV * HD) + kvh * HD + slot * 8]);
            *reinterpret_cast<bf16x8*>(&Vts[row * 64 + (slot ^ (row & 7)) * 8]) =
                *reinterpret_cast<const bf16x8*>(&Vtg[(size_t)(kvh * HD + row) * T_SEQ + k0 + slot * 8]);
        }
        if (tid < 128) {
            int row = tid >> 1, w = tid & 1;
            mlds[row][w] = selmask[(size_t)(q0 + row) * MASKW + (k0 >> 5) + w];
        }
        __syncthreads();

        f32x4 sacc[4];
#pragma unroll
        for (int j = 0; j < 4; ++j) sacc[j] = (f32x4){0.f, 0.f, 0.f, 0.f};
#pragma unroll
        for (int kc = 0; kc < 2; ++kc) {
            int arow_ = wid * 16 + fr;
            bf16x8 aq = *reinterpret_cast<const bf16x8*>(&Qs[arow_ * 64 + (((kc * 4 + fq) ^ (arow_ & 7))) * 8]);
#pragma unroll
            for (int jb = 0; jb < 4; ++jb) {
                int brow = jb * 16 + fr;
                bf16x8 bk = *reinterpret_cast<const bf16x8*>(&Ks[brow * 64 + (((kc * 4 + fq) ^ (brow & 7))) * 8]);
                sacc[jb] = __builtin_amdgcn_mfma_f32_16x16x32_bf16(aq, bk, sacc[jb], 0, 0, 0);
            }
        }
        // branchless bias + write S to LDS
#pragma unroll
        for (int jb = 0; jb < 4; ++jb)
#pragma unroll
            for (int r = 0; r < 4; ++r) {
                unsigned mw = mlds[wid * 16 + fq * 4 + r][jb >> 1];
                float bias = ((mw >> ((jb & 1) * 16 + fr)) & 1u) ? 0.f : LOGEPS;
                Sb[wid * 16 + fq * 4 + r][jb * 16 + fr] = sacc[jb][r] + bias;
            }
        __syncthreads();

        // online softmax, float4-vectorized: 4 threads per row
        {
            int r = tid >> 2, ln = tid & 3;
            float4* sp = reinterpret_cast<float4*>(&Sb[r][ln * 16]);
            float4 v0 = sp[0], v1 = sp[1], v2 = sp[2], v3 = sp[3];
            float mx = fmaxf(fmaxf(fmaxf(v0.x, v0.y), fmaxf(v0.z, v0.w)),
                             fmaxf(fmaxf(v1.x, v1.y), fmaxf(v1.z, v1.w)));
            mx = fmaxf(mx, fmaxf(fmaxf(fmaxf(v2.x, v2.y), fmaxf(v2.z, v2.w)),
                                 fmaxf(fmaxf(v3.x, v3.y), fmaxf(v3.z, v3.w))));
            mx = fmaxf(mx, __shfl_xor(mx, 1, 64));
            mx = fmaxf(mx, __shfl_xor(mx, 2, 64));
            float mnew = fmaxf(mrow[r], mx);
            v0.x = __expf(v0.x - mnew); v0.y = __expf(v0.y - mnew);
            v0.z = __expf(v0.z - mnew); v0.w = __expf(v0.w - mnew);
            v1.x = __expf(v1.x - mnew); v1.y = __expf(v1.y - mnew);
            v1.z = __expf(v1.z - mnew); v1.w = __expf(v1.w - mnew);
            v2.x = __expf(v2.x - mnew); v2.y = __expf(v2.y - mnew);
            v2.z = __expf(v2.z - mnew); v2.w = __expf(v2.w - mnew);
            v3.x = __expf(v3.x - mnew); v3.y = __expf(v3.y - mnew);
            v3.z = __expf(v3.z - mnew); v3.w = __expf(v3.w - mnew);
            float ssum = (v0.x + v0.y + v0.z + v0.w) + (v1.x + v1.y + v1.z + v1.w)
                       + (v2.x + v2.y + v2.z + v2.w) + (v3.x + v3.y + v3.z + v3.w);
            sp[0] = v0; sp[1] = v1; sp[2] = v2; sp[3] = v3;
            ssum += __shfl_xor(ssum, 1, 64);
            ssum += __shfl_xor(ssum, 2, 64);
            if (ln == 0) {
                float a = __expf(mrow[r] - mnew);
                lrow[r] = lrow[r] * a + ssum;
                mrow[r] = mnew;
                arow[r] = a;
            }
        }
        __syncthreads();

#pragma unroll
        for (int r = 0; r < 4; ++r) {
            float a = arow[wid * 16 + fq * 4 + r];
#pragma unroll
            for (int jb = 0; jb < 4; ++jb) oc[jb][r] *= a;
        }
#pragma unroll
        for (int kc = 0; kc < 2; ++kc) {
            const float* ps = &Sb[wid * 16 + fr][kc * 32 + fq * 8];
            float4 p0 = *reinterpret_cast<const float4*>(ps);
            float4 p1 = *reinterpret_cast<const float4*>(ps + 4);
            bf16x8 ap;
            ap[0] = (bf16_t)p0.x; ap[1] = (bf16_t)p0.y; ap[2] = (bf16_t)p0.z; ap[3] = (bf16_t)p0.w;
            ap[4] = (bf16_t)p1.x; ap[5] = (bf16_t)p1.y; ap[6] = (bf16_t)p1.z; ap[7] = (bf16_t)p1.w;
#pragma unroll
            for (int jb = 0; jb < 4; ++jb) {
                int brow = jb * 16 + fr;
                bf16x8 bv = *reinterpret_cast<const bf16x8*>(&Vts[brow * 64 + (((kc * 4 + fq) ^ (brow & 7))) * 8]);
                oc[jb] = __builtin_amdgcn_mfma_f32_16x16x32_bf16(ap, bv, oc[jb], 0, 0, 0);
            }
        }
        __syncthreads();
    }

#pragma unroll
    for (int r = 0; r < 4; ++r) {
        int rowl = wid * 16 + fq * 4 + r;
        float inv = 1.0f / lrow[rowl];
#pragma unroll
        for (int jb = 0; jb < 4; ++jb)
            yb[(size_t)(q0 + rowl) * C_DIM + h * HD + jb * 16 + fr] = oc[jb][r] * inv;
    }
}

// ---------------------------------------------------------------------------
extern "C" void kernel_launch(void* const* d_in, const int* in_sizes, int n_in,
                              void* d_out, int out_size, void* d_ws, size_t ws_size,
                              hipStream_t stream) {
    const float* x    = (const float*)d_in[0];
    const float* cosb = (const float*)d_in[1];
    const float* sinb = (const float*)d_in[2];
    const float* Wq   = (const float*)d_in[3];
    const float* Wk   = (const float*)d_in[4];
    const float* Wv   = (const float*)d_in[5];
    const float* Wo   = (const float*)d_in[6];
    const float* Wiq  = (const float*)d_in[7];
    const float* Wik  = (const float*)d_in[8];
    const float* Wiw  = (const float*)d_in[9];
    float* out = (float*)d_out;

    // ---- workspace carve (bytes) ----
    char* cur = (char*)d_ws;
    auto carve = [&](size_t bytes) { char* p = cur; cur += (bytes + 255) & ~(size_t)255; return p; };
    float*    qkvi  = (float*)   carve((size_t)T_SEQ * QKVI_N * 4);       // 26.7 MB
    float*    yb    = (float*)   carve((size_t)T_SEQ * C_DIM * 4);        // 12.6 MB
    unsigned* selm  = (unsigned*)carve((size_t)T_SEQ * MASKW * 4);        // 1.2 MB
    bf16_t*   Wtp   = (bf16_t*)  carve((size_t)QKVI_N * C_DIM * 2);       // 4.5 MB
    bf16_t*   Wot   = (bf16_t*)  carve((size_t)C_DIM * C_DIM * 2);        // 2.1 MB
    bf16_t*   Vtg   = (bf16_t*)  carve((size_t)NKV * HD * T_SEQ * 2);     // 1.5 MB
    bf16_t*   Kb16  = (bf16_t*)  carve((size_t)T_SEQ * NKV * HD * 2);     // 1.5 MB
    if ((size_t)(cur - (char*)d_ws) > ws_size) return;  // clean failure, not OOB

    dim3 blk(256);

    // 1. weights -> transposed bf16 (rows of Wtp: q|k|v|iq|ik|iw|pad-garbage)
    transp_conv<<<dim3(16, 16), blk, 0, stream>>>(Wq,  Wtp + (size_t)0    * 1024, 1024);
    transp_conv<<<dim3(4, 16),  blk, 0, stream>>>(Wk,  Wtp + (size_t)1024 * 1024, 256);
    transp_conv<<<dim3(4, 16),  blk, 0, stream>>>(Wv,  Wtp + (size_t)1280 * 1024, 256);
    transp_conv<<<dim3(8, 16),  blk, 0, stream>>>(Wiq, Wtp + (size_t)IQ_OFF * 1024, 512);
    transp_conv_g<<<dim3(1, 16), blk, 0, stream>>>(Wik, Wtp + (size_t)IK_OFF * 1024, DI);
    transp_conv_g<<<dim3(1, 16), blk, 0, stream>>>(Wiw, Wtp + (size_t)IW_OFF * 1024, HI);
    transp_conv<<<dim3(16, 16), blk, 0, stream>>>(Wo,  Wot, 1024);

    // 2. fused projection GEMM (q|k|v|iq|ik|iw) via MFMA; causal bias rows
    gemm_mfma_t<true><<<dim3(QKVI_N / 128, T_SEQ / 128), blk, 0, stream>>>(x, Wtp, qkvi, QKVI_N);
    causal_mask<<<(SELQ0 * MASKW + 255) / 256, blk, 0, stream>>>(selm);

    // 3. RoPE + RMS on q/k in place; pack K (bf16) + V (transposed bf16)
    rope_rms<<<(T_SEQ * NH + 255) / 256, blk, 0, stream>>>(qkvi, cosb, sinb, NH, QKVI_N, 0);
    rope_rms<<<(T_SEQ * NKV + 255) / 256, blk, 0, stream>>>(qkvi, cosb, sinb, NKV, QKVI_N, 1024);
    pack_kv<<<dim3(T_SEQ / 64, NKV), blk, 0, stream>>>(qkvi, Kb16, Vtg);

    // 4. top-R selection masks (MFMA scores + radix select, diag bit included)
    imp_select<<<T_SEQ - SELQ0, blk, 0, stream>>>(qkvi, selm);

    // 5. MFMA attention
    attn_mfma<<<dim3(T_SEQ / 64, NH), blk, 0, stream>>>(qkvi, Kb16, Vtg, selm, yb);

    // 6. output projection via MFMA
    gemm_mfma_t<true><<<dim3(C_DIM / 128, T_SEQ / 128), blk, 0, stream>>>(yb, Wot, out, C_DIM);
}

// Round 14
// 419.612 us; speedup vs baseline: 3.0232x; 1.0240x over previous
//
#include <hip/hip_runtime.h>
#include <hip/hip_bf16.h>
#include <math.h>

#define T_SEQ   3072
#define C_DIM   1024
#define NH      16
#define NKV     4
#define HD      64
#define HI      16
#define DI      32
#define LOCAL_W 128
#define TOPK    1536
#define SELQ0   (TOPK - LOCAL_W + 1)   /* 1409 */
#define RMS_EPS 1.1920929e-07f
#define LOGEPS  -13.815510558f
#define SCALE   0.125f
#define MASKW   (T_SEQ / 32)
#define QKVI_N  2176                   /* q(1024)|k(256)|v(256)|iq(512)|ik(32)|iw(16)|pad(80) */
#define IQ_OFF  1536
#define IK_OFF  2048
#define IW_OFF  2080

typedef __bf16 bf16_t;
typedef __bf16 bf16x8 __attribute__((ext_vector_type(8)));
typedef float  f32x4  __attribute__((ext_vector_type(4)));

static __device__ inline unsigned packbf(float a, float b) {
    union { bf16_t h[2]; unsigned u; } cv;
    cv.h[0] = (bf16_t)a; cv.h[1] = (bf16_t)b;
    return cv.u;
}

// ---------------------------------------------------------------------------
// W[K=1024][N] fp32 -> Wt[N][1024] bf16 (transpose+convert), 64x64 tiles, N%64==0
// ---------------------------------------------------------------------------
__global__ __launch_bounds__(256) void transp_conv(const float* __restrict__ W,
                                                   bf16_t* __restrict__ Wt, int N) {
    __shared__ float t[64][65];
    int n0 = blockIdx.x * 64, k0 = blockIdx.y * 64;
#pragma unroll
    for (int it = 0; it < 16; ++it) {
        int flat = it * 256 + threadIdx.x;
        int i = flat >> 6, j = flat & 63;
        t[i][j] = W[(size_t)(k0 + i) * N + n0 + j];
    }
    __syncthreads();
#pragma unroll
    for (int it = 0; it < 16; ++it) {
        int flat = it * 256 + threadIdx.x;
        int n = flat >> 6, kk = flat & 63;
        Wt[(size_t)(n0 + n) * 1024 + k0 + kk] = (bf16_t)t[kk][n];
    }
}

// Guarded variant for skinny N (<64): reads padded with 0, writes only n<N rows.
__global__ __launch_bounds__(256) void transp_conv_g(const float* __restrict__ W,
                                                     bf16_t* __restrict__ Wt, int N) {
    __shared__ float t[64][65];
    int k0 = blockIdx.y * 64;
#pragma unroll
    for (int it = 0; it < 16; ++it) {
        int flat = it * 256 + threadIdx.x;
        int i = flat >> 6, j = flat & 63;
        t[i][j] = (j < N) ? W[(size_t)(k0 + i) * N + j] : 0.f;
    }
    __syncthreads();
#pragma unroll
    for (int it = 0; it < 16; ++it) {
        int flat = it * 256 + threadIdx.x;
        int n = flat >> 6, kk = flat & 63;
        if (n < N) Wt[(size_t)n * 1024 + k0 + kk] = (bf16_t)t[kk][n];
    }
}

// ---------------------------------------------------------------------------
// K region -> Kb bf16 [t][kvh*64+d] and V region -> Vtg bf16 [kvh*64+d][T].
// ---------------------------------------------------------------------------
__global__ __launch_bounds__(256) void pack_kv(const float* __restrict__ qkvi,
                                               bf16_t* __restrict__ Kb,
                                               bf16_t* __restrict__ Vtg) {
    __shared__ float t[64][65];
    int t0 = blockIdx.x * 64, kvh = blockIdx.y;
#pragma unroll
    for (int it = 0; it < 2; ++it) {
        int s = it * 256 + threadIdx.x;
        int row = s >> 3, slot = s & 7;
        const float* src = &qkvi[(size_t)(t0 + row) * QKVI_N + 1024 + kvh * HD + slot * 8];
        float4 a = *reinterpret_cast<const float4*>(src);
        float4 b = *reinterpret_cast<const float4*>(src + 4);
        bf16x8 v;
        v[0] = (bf16_t)a.x; v[1] = (bf16_t)a.y; v[2] = (bf16_t)a.z; v[3] = (bf16_t)a.w;
        v[4] = (bf16_t)b.x; v[5] = (bf16_t)b.y; v[6] = (bf16_t)b.z; v[7] = (bf16_t)b.w;
        *reinterpret_cast<bf16x8*>(&Kb[(size_t)(t0 + row) * (NKV * HD) + kvh * HD + slot * 8]) = v;
    }
#pragma unroll
    for (int it = 0; it < 16; ++it) {
        int flat = it * 256 + threadIdx.x;
        int i = flat >> 6, j = flat & 63;
        t[i][j] = qkvi[(size_t)(t0 + i) * QKVI_N + 1280 + kvh * HD + j];
    }
    __syncthreads();
#pragma unroll
    for (int it = 0; it < 16; ++it) {
        int flat = it * 256 + threadIdx.x;
        int dd = flat >> 6, tt = flat & 63;
        Vtg[(size_t)(kvh * HD + dd) * T_SEQ + t0 + tt] = (bf16_t)t[tt][dd];
    }
}

// ---------------------------------------------------------------------------
// Bias bitmask for rows [0, SELQ0): bit k set (bias 0) iff k <= row.
// ---------------------------------------------------------------------------
__global__ __launch_bounds__(256) void causal_mask(unsigned* __restrict__ selm) {
    int idx = blockIdx.x * 256 + threadIdx.x;
    if (idx >= SELQ0 * MASKW) return;
    int row = idx / MASKW, w = idx % MASKW;
    int wq = row >> 5, b = row & 31;
    unsigned v;
    if (w < wq) v = ~0u;
    else if (w == wq) v = (b == 31) ? ~0u : ((1u << (b + 1)) - 1u);
    else v = 0u;
    selm[(size_t)row * MASKW + w] = v;
}

// ---------------------------------------------------------------------------
// bf16 MFMA GEMM: C[M][N] = A[M][1024] @ Bt[N][1024]^T, fp32 out.
// ---------------------------------------------------------------------------
template<bool A_F32>
__global__ __launch_bounds__(256) void gemm_mfma_t(const void* __restrict__ Ap,
                                                   const bf16_t* __restrict__ Bt,
                                                   float* __restrict__ C, int N) {
    __shared__ __align__(16) bf16_t As[128 * 64];
    __shared__ __align__(16) bf16_t Bs[128 * 64];
    const int tid = threadIdx.x;
    const int m0 = blockIdx.y * 128, n0 = blockIdx.x * 128;
    const int wid = tid >> 6, lane = tid & 63;
    const int wr = wid >> 1, wc = wid & 1;
    const int fr = lane & 15, fq = lane >> 4;

    f32x4 acc[4][4];
#pragma unroll
    for (int i = 0; i < 4; ++i)
#pragma unroll
        for (int j = 0; j < 4; ++j) acc[i][j] = (f32x4){0.f, 0.f, 0.f, 0.f};

    for (int k0 = 0; k0 < 1024; k0 += 64) {
        __syncthreads();
#pragma unroll
        for (int s = tid; s < 1024; s += 256) {
            int row = s >> 3, slot = s & 7;
            int sw = slot ^ (row & 7);
            bf16x8 av;
            if constexpr (A_F32) {
                const float* A = (const float*)Ap;
                const float* src = &A[(size_t)(m0 + row) * 1024 + k0 + slot * 8];
                float4 a = *reinterpret_cast<const float4*>(src);
                float4 b = *reinterpret_cast<const float4*>(src + 4);
                av[0] = (bf16_t)a.x; av[1] = (bf16_t)a.y; av[2] = (bf16_t)a.z; av[3] = (bf16_t)a.w;
                av[4] = (bf16_t)b.x; av[5] = (bf16_t)b.y; av[6] = (bf16_t)b.z; av[7] = (bf16_t)b.w;
            } else {
                const bf16_t* A = (const bf16_t*)Ap;
                av = *reinterpret_cast<const bf16x8*>(&A[(size_t)(m0 + row) * 1024 + k0 + slot * 8]);
            }
            *reinterpret_cast<bf16x8*>(&As[row * 64 + sw * 8]) = av;
            bf16x8 bv = *reinterpret_cast<const bf16x8*>(&Bt[(size_t)(n0 + row) * 1024 + k0 + slot * 8]);
            *reinterpret_cast<bf16x8*>(&Bs[row * 64 + sw * 8]) = bv;
        }
        __syncthreads();
#pragma unroll
        for (int kk = 0; kk < 2; ++kk) {
            bf16x8 af[4], bfr[4];
#pragma unroll
            for (int i = 0; i < 4; ++i) {
                int arow = wr * 64 + i * 16 + fr;
                int aslot = (kk * 4 + fq) ^ (arow & 7);
                af[i] = *reinterpret_cast<const bf16x8*>(&As[arow * 64 + aslot * 8]);
                int brow = wc * 64 + i * 16 + fr;
                int bslot = (kk * 4 + fq) ^ (brow & 7);
                bfr[i] = *reinterpret_cast<const bf16x8*>(&Bs[brow * 64 + bslot * 8]);
            }
#pragma unroll
            for (int i = 0; i < 4; ++i)
#pragma unroll
                for (int j = 0; j < 4; ++j)
                    acc[i][j] = __builtin_amdgcn_mfma_f32_16x16x32_bf16(af[i], bfr[j], acc[i][j], 0, 0, 0);
        }
    }
#pragma unroll
    for (int i = 0; i < 4; ++i)
#pragma unroll
        for (int j = 0; j < 4; ++j)
#pragma unroll
            for (int r = 0; r < 4; ++r) {
                int row = m0 + wr * 64 + i * 16 + fq * 4 + r;
                int col = n0 + wc * 64 + j * 16 + fr;
                C[(size_t)row * N + col] = acc[i][j][r];
            }
}

// ---------------------------------------------------------------------------
// RoPE + RMS norm, in place, strided fused-buffer layout.
// ---------------------------------------------------------------------------
__global__ __launch_bounds__(256) void rope_rms(float* __restrict__ data,
                                                const float* __restrict__ cosb,
                                                const float* __restrict__ sinb,
                                                int nheads, int rowstride, int coloff) {
    int idx = blockIdx.x * blockDim.x + threadIdx.x;
    if (idx >= T_SEQ * nheads) return;
    int t = idx / nheads, hh = idx % nheads;
    float* p = data + (size_t)t * rowstride + coloff + hh * HD;
    float o[HD];
    float ss = 0.f;
#pragma unroll
    for (int d = 0; d < 32; ++d) {
        float x1 = p[d], x2 = p[d + 32];
        float c = cosb[t * 32 + d], s = sinb[t * 32 + d];
        float a = x1 * c + x2 * s;
        float b = x2 * c - x1 * s;
        o[d] = a; o[d + 32] = b;
        ss += a * a + b * b;
    }
    float r = 1.0f / sqrtf(ss * (1.0f / HD) + RMS_EPS);
#pragma unroll
    for (int d = 0; d < HD; ++d) p[d] = o[d] * r;
}

// ---------------------------------------------------------------------------
// Importance scores via MFMA + exact top-R radix select, rows q in [SELQ0,T).
// Output mask includes the diagonal bit. Tie-break lowest-index.
// ---------------------------------------------------------------------------
__global__ __launch_bounds__(256) void imp_select(const float* __restrict__ qkvi,
                                                  unsigned* __restrict__ selmask) {
    const int q = SELQ0 + blockIdx.x;
    const int tid = threadIdx.x;
    const int wid = tid >> 6, lane = tid & 63;
    const int fr = lane & 15, fq = lane >> 4;

    __shared__ unsigned keys[T_SEQ];
    __shared__ unsigned hist[256];
    __shared__ int sufx[257];
    __shared__ unsigned gtw[MASKW], eqw[MASKW];
    __shared__ int s_digit, s_need;

    const float* iqp = &qkvi[(size_t)q * QKVI_N + IQ_OFF + fr * DI + fq * 8];
    float4 qa = *reinterpret_cast<const float4*>(iqp);
    float4 qb = *reinterpret_cast<const float4*>(iqp + 4);
    bf16x8 bq;
    bq[0] = (bf16_t)qa.x; bq[1] = (bf16_t)qa.y; bq[2] = (bf16_t)qa.z; bq[3] = (bf16_t)qa.w;
    bq[4] = (bf16_t)qb.x; bq[5] = (bf16_t)qb.y; bq[6] = (bf16_t)qb.z; bq[7] = (bf16_t)qb.w;
    const float wh = qkvi[(size_t)q * QKVI_N + IW_OFF + fr];

    for (int k0 = 0; k0 < q; k0 += 64) {
        int krow = k0 + wid * 16 + fr;
        const float* ikp = &qkvi[(size_t)krow * QKVI_N + IK_OFF + fq * 8];
        float4 a = *reinterpret_cast<const float4*>(ikp);
        float4 b = *reinterpret_cast<const float4*>(ikp + 4);
        bf16x8 ak;
        ak[0] = (bf16_t)a.x; ak[1] = (bf16_t)a.y; ak[2] = (bf16_t)a.z; ak[3] = (bf16_t)a.w;
        ak[4] = (bf16_t)b.x; ak[5] = (bf16_t)b.y; ak[6] = (bf16_t)b.z; ak[7] = (bf16_t)b.w;
        f32x4 c = (f32x4){0.f, 0.f, 0.f, 0.f};
        c = __builtin_amdgcn_mfma_f32_16x16x32_bf16(ak, bq, c, 0, 0, 0);
        float p0 = wh * fmaxf(c[0], 0.f);
        float p1 = wh * fmaxf(c[1], 0.f);
        float p2 = wh * fmaxf(c[2], 0.f);
        float p3 = wh * fmaxf(c[3], 0.f);
#pragma unroll
        for (int m = 1; m < 16; m <<= 1) {
            p0 += __shfl_xor(p0, m);
            p1 += __shfl_xor(p1, m);
            p2 += __shfl_xor(p2, m);
            p3 += __shfl_xor(p3, m);
        }
        if (fr == 0) {
            int kb = k0 + wid * 16 + fq * 4;
            float pv[4] = {p0, p1, p2, p3};
#pragma unroll
            for (int r = 0; r < 4; ++r) {
                int k = kb + r;
                if (k < q) {
                    unsigned u = __float_as_uint(pv[r]);
                    keys[k] = (u & 0x80000000u) ? ~u : (u | 0x80000000u);
                }
            }
        }
    }
    __syncthreads();

    const int F = min(LOCAL_W, T_SEQ - q);
    int need = TOPK - F;
    unsigned pref = 0;
    for (int b = 3; b >= 0; --b) {
        hist[tid] = 0;
        __syncthreads();
        unsigned above = (b == 3) ? 0u : (~0u << ((b + 1) * 8));
        for (int k = tid; k < q; k += 256) {
            unsigned key = keys[k];
            if ((key & above) == (pref & above))
                atomicAdd(&hist[(key >> (b * 8)) & 255u], 1u);
        }
        __syncthreads();
        sufx[tid] = (int)hist[tid];
        if (tid == 0) sufx[256] = 0;
        __syncthreads();
        for (int s = 1; s < 256; s <<= 1) {
            int v = sufx[tid] + ((tid + s < 256) ? sufx[tid + s] : 0);
            __syncthreads();
            sufx[tid] = v;
            __syncthreads();
        }
        int nxt = sufx[tid + 1];
        if (sufx[tid] >= need && nxt < need) { s_digit = tid; s_need = need - nxt; }
        __syncthreads();
        pref |= ((unsigned)s_digit) << (b * 8);
        need = s_need;
        __syncthreads();
    }
    const unsigned V = pref;
    const int slots = need;

    for (int w = tid; w < MASKW; w += 256) {
        unsigned g = 0, e = 0;
        int kbase = w * 32;
#pragma unroll 4
        for (int bit = 0; bit < 32; ++bit) {
            int k = kbase + bit;
            if (k < q) {
                unsigned key = keys[k];
                if (key > V) g |= (1u << bit);
                else if (key == V) e |= (1u << bit);
            }
        }
        gtw[w] = g; eqw[w] = e;
    }
    __syncthreads();
    if (tid == 0) {
        int rem = slots;
        for (int w = 0; w < MASKW && rem > 0; ++w) {
            unsigned e = eqw[w];
            if (!e) continue;
            int pc = __popc(e);
            if (pc <= rem) { gtw[w] |= e; rem -= pc; }
            else {
                unsigned sel = 0;
                for (int i = 0; i < rem; ++i) { unsigned lb = e & (~e + 1u); sel |= lb; e ^= lb; }
                gtw[w] |= sel; rem = 0;
            }
        }
    }
    __syncthreads();
    for (int w = tid; w < MASKW; w += 256) {
        unsigned g = gtw[w];
        if (w == (q >> 5)) g |= (1u << (q & 31));   // diagonal: bias 0
        selmask[(size_t)q * MASKW + w] = g;
    }
}

// ---------------------------------------------------------------------------
// MFMA attention, swapped-QK + in-register softmax.
// One block per (64-q-tile, head), 4 waves; wave owns q-rows [wid*16,wid*16+16).
// QK^T: mfma(A=K, B=Q) -> lane (fr,fq) holds S[key=jb*16+4fq+r][q=fr].
// Softmax entirely in registers (stats replicated over the 4 fq lanes).
// P redistributed to PV A-fragment layout via 16 shfl + 8 selects.
// ---------------------------------------------------------------------------
__global__ __launch_bounds__(256) void attn_mfma(const float* __restrict__ qkvi,
                                                 const bf16_t* __restrict__ Kb,
                                                 const bf16_t* __restrict__ Vtg,
                                                 const unsigned* __restrict__ selmask,
                                                 float* __restrict__ yb) {
    const int q0 = blockIdx.x * 64;
    const int h = blockIdx.y;
    const int kvh = h >> 2;
    const int tid = threadIdx.x;
    const int wid = tid >> 6, lane = tid & 63;
    const int fr = lane & 15, fq = lane >> 4;

    __shared__ __align__(16) bf16_t Ks[64 * 64];
    __shared__ __align__(16) bf16_t Vts[64 * 64];   // [d][key]
    __shared__ unsigned mlds[64][2];

    // Q fragments in registers (B-operand: col(n)=fr -> q-row, k=kc*32+fq*8+j)
    bf16x8 qf[2];
    {
        const float* qsrc = &qkvi[(size_t)(q0 + wid * 16 + fr) * QKVI_N + h * HD];
#pragma unroll
        for (int kc = 0; kc < 2; ++kc) {
            float4 a = *reinterpret_cast<const float4*>(qsrc + kc * 32 + fq * 8);
            float4 b = *reinterpret_cast<const float4*>(qsrc + kc * 32 + fq * 8 + 4);
            bf16x8 v;
            v[0] = (bf16_t)(a.x * SCALE); v[1] = (bf16_t)(a.y * SCALE);
            v[2] = (bf16_t)(a.z * SCALE); v[3] = (bf16_t)(a.w * SCALE);
            v[4] = (bf16_t)(b.x * SCALE); v[5] = (bf16_t)(b.y * SCALE);
            v[6] = (bf16_t)(b.z * SCALE); v[7] = (bf16_t)(b.w * SCALE);
            qf[kc] = v;
        }
    }

    float m_reg = -1e30f, l_reg = 0.f;
    f32x4 oc[4];
#pragma unroll
    for (int j = 0; j < 4; ++j) oc[j] = (f32x4){0.f, 0.f, 0.f, 0.f};

    for (int k0 = 0; k0 < T_SEQ; k0 += 64) {
        __syncthreads();   // previous tile's LDS reads complete
#pragma unroll
        for (int it = 0; it < 2; ++it) {
            int s = it * 256 + tid;
            int row = s >> 3, slot = s & 7;
            *reinterpret_cast<bf16x8*>(&Ks[row * 64 + (slot ^ (row & 7)) * 8]) =
                *reinterpret_cast<const bf16x8*>(&Kb[(size_t)(k0 + row) * (NKV * HD) + kvh * HD + slot * 8]);
            *reinterpret_cast<bf16x8*>(&Vts[row * 64 + (slot ^ (row & 7)) * 8]) =
                *reinterpret_cast<const bf16x8*>(&Vtg[(size_t)(kvh * HD + row) * T_SEQ + k0 + slot * 8]);
        }
        if (tid < 128) {
            int row = tid >> 1, w = tid & 1;
            mlds[row][w] = selmask[(size_t)(q0 + row) * MASKW + (k0 >> 5) + w];
        }
        __syncthreads();

        // QK^T swapped: sacc[jb][r] = S[key = jb*16+4*fq+r][q = fr]
        f32x4 sacc[4];
#pragma unroll
        for (int j = 0; j < 4; ++j) sacc[j] = (f32x4){0.f, 0.f, 0.f, 0.f};
#pragma unroll
        for (int kc = 0; kc < 2; ++kc) {
#pragma unroll
            for (int jb = 0; jb < 4; ++jb) {
                int arow = jb * 16 + fr;
                bf16x8 ak = *reinterpret_cast<const bf16x8*>(&Ks[arow * 64 + (((kc * 4 + fq) ^ (arow & 7))) * 8]);
                sacc[jb] = __builtin_amdgcn_mfma_f32_16x16x32_bf16(ak, qf[kc], sacc[jb], 0, 0, 0);
            }
        }

        // bias + online softmax in registers (q-row = fr)
        unsigned mw0 = mlds[wid * 16 + fr][0];
        unsigned mw1 = mlds[wid * 16 + fr][1];
        float p[4][4];
        float mx = -1e30f;
#pragma unroll
        for (int jb = 0; jb < 4; ++jb) {
            unsigned mw = (jb & 2) ? mw1 : mw0;
#pragma unroll
            for (int r = 0; r < 4; ++r) {
                float bias = ((mw >> ((jb & 1) * 16 + 4 * fq + r)) & 1u) ? 0.f : LOGEPS;
                p[jb][r] = sacc[jb][r] + bias;
                mx = fmaxf(mx, p[jb][r]);
            }
        }
        mx = fmaxf(mx, __shfl_xor(mx, 16, 64));
        mx = fmaxf(mx, __shfl_xor(mx, 32, 64));
        float mnew = fmaxf(m_reg, mx);
        float aold = __expf(m_reg - mnew);
        float ssum = 0.f;
#pragma unroll
        for (int jb = 0; jb < 4; ++jb)
#pragma unroll
            for (int r = 0; r < 4; ++r) {
                p[jb][r] = __expf(p[jb][r] - mnew);
                ssum += p[jb][r];
            }
        ssum += __shfl_xor(ssum, 16, 64);
        ssum += __shfl_xor(ssum, 32, 64);
        l_reg = l_reg * aold + ssum;
        m_reg = mnew;

        // pack P (bf16 pairs): w32[jb][rp] = keys 16jb+4fq+2rp..+1 of q-row fr
        unsigned w32[4][2];
#pragma unroll
        for (int jb = 0; jb < 4; ++jb) {
            w32[jb][0] = packbf(p[jb][0], p[jb][1]);
            w32[jb][1] = packbf(p[jb][2], p[jb][3]);
        }

        // redistribute to PV A-fragment: n32[kc][jp] = keys kc*32+8fq+2jp..+1
        // = w32[2kc+(fq>>1)][jp&1] from lane fr + 16*(2*(fq&1)+(jp>>1))
        unsigned n32[2][4];
#pragma unroll
        for (int kc = 0; kc < 2; ++kc)
#pragma unroll
            for (int jp = 0; jp < 4; ++jp) {
                int src = fr + 16 * (2 * (fq & 1) + (jp >> 1));
                unsigned lo = __shfl(w32[2 * kc][jp & 1], src, 64);
                unsigned hi = __shfl(w32[2 * kc + 1][jp & 1], src, 64);
                n32[kc][jp] = (fq >> 1) ? hi : lo;
            }

        // rescale O: oc[jb][r] belongs to q-row 4fq+r -> fetch that row's aold
        float a4[4];
#pragma unroll
        for (int r = 0; r < 4; ++r) a4[r] = __shfl(aold, 4 * fq + r, 64);
#pragma unroll
        for (int jb = 0; jb < 4; ++jb)
#pragma unroll
            for (int r = 0; r < 4; ++r) oc[jb][r] *= a4[r];

        // PV: D[m=q][n=d] with A=P, B=V^T rows
#pragma unroll
        for (int kc = 0; kc < 2; ++kc) {
            union { unsigned u[4]; bf16x8 v; } cv;
            cv.u[0] = n32[kc][0]; cv.u[1] = n32[kc][1];
            cv.u[2] = n32[kc][2]; cv.u[3] = n32[kc][3];
#pragma unroll
            for (int jb = 0; jb < 4; ++jb) {
                int brow = jb * 16 + fr;
                bf16x8 bv = *reinterpret_cast<const bf16x8*>(&Vts[brow * 64 + (((kc * 4 + fq) ^ (brow & 7))) * 8]);
                oc[jb] = __builtin_amdgcn_mfma_f32_16x16x32_bf16(cv.v, bv, oc[jb], 0, 0, 0);
            }
        }
    }

    // epilogue: oc[jb][r] is q-row 4fq+r, d = jb*16+fr
    float inv4[4];
#pragma unroll
    for (int r = 0; r < 4; ++r) inv4[r] = 1.0f / __shfl(l_reg, 4 * fq + r, 64);
#pragma unroll
    for (int r = 0; r < 4; ++r) {
        int rowl = wid * 16 + fq * 4 + r;
#pragma unroll
        for (int jb = 0; jb < 4; ++jb)
            yb[(size_t)(q0 + rowl) * C_DIM + h * HD + jb * 16 + fr] = oc[jb][r] * inv4[r];
    }
}

// ---------------------------------------------------------------------------
extern "C" void kernel_launch(void* const* d_in, const int* in_sizes, int n_in,
                              void* d_out, int out_size, void* d_ws, size_t ws_size,
                              hipStream_t stream) {
    const float* x    = (const float*)d_in[0];
    const float* cosb = (const float*)d_in[1];
    const float* sinb = (const float*)d_in[2];
    const float* Wq   = (const float*)d_in[3];
    const float* Wk   = (const float*)d_in[4];
    const float* Wv   = (const float*)d_in[5];
    const float* Wo   = (const float*)d_in[6];
    const float* Wiq  = (const float*)d_in[7];
    const float* Wik  = (const float*)d_in[8];
    const float* Wiw  = (const float*)d_in[9];
    float* out = (float*)d_out;

    // ---- workspace carve (bytes) ----
    char* cur = (char*)d_ws;
    auto carve = [&](size_t bytes) { char* p = cur; cur += (bytes + 255) & ~(size_t)255; return p; };
    float*    qkvi  = (float*)   carve((size_t)T_SEQ * QKVI_N * 4);       // 26.7 MB
    float*    yb    = (float*)   carve((size_t)T_SEQ * C_DIM * 4);        // 12.6 MB
    unsigned* selm  = (unsigned*)carve((size_t)T_SEQ * MASKW * 4);        // 1.2 MB
    bf16_t*   Wtp   = (bf16_t*)  carve((size_t)QKVI_N * C_DIM * 2);       // 4.5 MB
    bf16_t*   Wot   = (bf16_t*)  carve((size_t)C_DIM * C_DIM * 2);        // 2.1 MB
    bf16_t*   Vtg   = (bf16_t*)  carve((size_t)NKV * HD * T_SEQ * 2);     // 1.5 MB
    bf16_t*   Kb16  = (bf16_t*)  carve((size_t)T_SEQ * NKV * HD * 2);     // 1.5 MB
    if ((size_t)(cur - (char*)d_ws) > ws_size) return;  // clean failure, not OOB

    dim3 blk(256);

    // 1. weights -> transposed bf16 (rows of Wtp: q|k|v|iq|ik|iw|pad-garbage)
    transp_conv<<<dim3(16, 16), blk, 0, stream>>>(Wq,  Wtp + (size_t)0    * 1024, 1024);
    transp_conv<<<dim3(4, 16),  blk, 0, stream>>>(Wk,  Wtp + (size_t)1024 * 1024, 256);
    transp_conv<<<dim3(4, 16),  blk, 0, stream>>>(Wv,  Wtp + (size_t)1280 * 1024, 256);
    transp_conv<<<dim3(8, 16),  blk, 0, stream>>>(Wiq, Wtp + (size_t)IQ_OFF * 1024, 512);
    transp_conv_g<<<dim3(1, 16), blk, 0, stream>>>(Wik, Wtp + (size_t)IK_OFF * 1024, DI);
    transp_conv_g<<<dim3(1, 16), blk, 0, stream>>>(Wiw, Wtp + (size_t)IW_OFF * 1024, HI);
    transp_conv<<<dim3(16, 16), blk, 0, stream>>>(Wo,  Wot, 1024);

    // 2. fused projection GEMM (q|k|v|iq|ik|iw) via MFMA; causal bias rows
    gemm_mfma_t<true><<<dim3(QKVI_N / 128, T_SEQ / 128), blk, 0, stream>>>(x, Wtp, qkvi, QKVI_N);
    causal_mask<<<(SELQ0 * MASKW + 255) / 256, blk, 0, stream>>>(selm);

    // 3. RoPE + RMS on q/k in place; pack K (bf16) + V (transposed bf16)
    rope_rms<<<(T_SEQ * NH + 255) / 256, blk, 0, stream>>>(qkvi, cosb, sinb, NH, QKVI_N, 0);
    rope_rms<<<(T_SEQ * NKV + 255) / 256, blk, 0, stream>>>(qkvi, cosb, sinb, NKV, QKVI_N, 1024);
    pack_kv<<<dim3(T_SEQ / 64, NKV), blk, 0, stream>>>(qkvi, Kb16, Vtg);

    // 4. top-R selection masks (MFMA scores + radix select, diag bit included)
    imp_select<<<T_SEQ - SELQ0, blk, 0, stream>>>(qkvi, selm);

    // 5. MFMA attention (swapped-QK, in-register softmax)
    attn_mfma<<<dim3(T_SEQ / 64, NH), blk, 0, stream>>>(qkvi, Kb16, Vtg, selm, yb);

    // 6. output projection via MFMA
    gemm_mfma_t<true><<<dim3(C_DIM / 128, T_SEQ / 128), blk, 0, stream>>>(yb, Wot, out, C_DIM);
}